// Round 5
// baseline (707.231 us; speedup 1.0000x reference)
//
#include <hip/hip_runtime.h>
#include <hip/hip_bf16.h>

// ---------------- CSR build ----------------
__global__ __launch_bounds__(256) void hist_kernel(
    const int* __restrict__ dst, int* __restrict__ deg, int E)
{
    int e = blockIdx.x * blockDim.x + threadIdx.x;
    if (e < E) atomicAdd(&deg[dst[e]], 1);
}

// single-workgroup scan, wave-shfl based (few barriers)
__global__ __launch_bounds__(1024) void scan_kernel(
    const int* __restrict__ deg, int* __restrict__ rowptr,
    int* __restrict__ cursor, int N)
{
    __shared__ int wsum[16];
    __shared__ int wpre[16];
    __shared__ int chunk_total;
    __shared__ int carry_s;
    const int tid = threadIdx.x, wave = tid >> 6, lane = tid & 63;
    if (tid == 0) carry_s = 0;
    __syncthreads();
    for (int base = 0; base < N; base += 1024) {
        int i = base + tid;
        int val = (i < N) ? deg[i] : 0;
        int inc = val;
#pragma unroll
        for (int off = 1; off < 64; off <<= 1) {
            int t = __shfl_up(inc, off, 64);
            if (lane >= off) inc += t;
        }
        if (lane == 63) wsum[wave] = inc;
        __syncthreads();
        if (wave == 0) {
            int s = (lane < 16) ? wsum[lane] : 0;
#pragma unroll
            for (int off = 1; off < 16; off <<= 1) {
                int t = __shfl_up(s, off, 64);
                if (lane >= off) s += t;
            }
            if (lane < 16) wpre[lane] = s - wsum[lane];
            if (lane == 15) chunk_total = s;
        }
        __syncthreads();
        int exc = carry_s + wpre[wave] + inc - val;
        if (i < N) { rowptr[i] = exc; cursor[i] = exc; }
        __syncthreads();
        if (tid == 0) carry_s += chunk_total;
        __syncthreads();
    }
    if (tid == 0) rowptr[N] = carry_s;
}

__global__ __launch_bounds__(256) void fill_kernel(
    const int* __restrict__ src, const int* __restrict__ dst,
    int* __restrict__ cursor, int* __restrict__ perm, int E)
{
    int e = blockIdx.x * blockDim.x + threadIdx.x;
    if (e >= E) return;
    int pos = atomicAdd(&cursor[dst[e]], 1);
    perm[pos] = src[e];
}

// ---------------- K1: fused projection q/k/v/skip ----------------
// Block = 13 waves (832 thr), 64 nodes. Lane = node. Waves 0..11: matrix
// (wave/4) in {q,k,v}, col-group (wave%4)*32, acc[32] in VGPRs; weights via
// wave-uniform scalar loads (SGPR-operand FMAs). Wave 12: skip = x@ws+bs.
// x staged in LDS with +1 pad: read bank = (lane+k)%32, 2-way = free.
template <int L>
__global__ __launch_bounds__(832) void proj_kernel(
    const float* __restrict__ xin,
    const float* __restrict__ wq, const float* __restrict__ bq,
    const float* __restrict__ wk, const float* __restrict__ bk,
    const float* __restrict__ wv, const float* __restrict__ bv,
    const float* __restrict__ ws, const float* __restrict__ bs,
    float* __restrict__ q, float* __restrict__ k, float* __restrict__ v,
    float* __restrict__ skip, int N)
{
    __shared__ float xs[64 * (L + 1)];
    const int tid = threadIdx.x;
    const int lane = tid & 63;
    const int n0 = blockIdx.x * 64;
    constexpr int L4 = L / 4;
    for (int f = tid; f < 64 * L4; f += 832) {
        int row = f / L4, c4 = (f - row * L4) * 4;
        int n = n0 + row;
        float4 val = (n < N) ? *(const float4*)(xin + (long)n * L + c4)
                             : make_float4(0.f, 0.f, 0.f, 0.f);
        float* p = xs + row * (L + 1) + c4;
        p[0] = val.x; p[1] = val.y; p[2] = val.z; p[3] = val.w;
    }
    __syncthreads();

    const int wv_ = __builtin_amdgcn_readfirstlane(tid >> 6);  // 0..12, uniform
    const int n = n0 + lane;
    const float* xrow = xs + lane * (L + 1);

    if (wv_ < 12) {
        const int mat = wv_ >> 2;
        const int c0 = (wv_ & 3) * 32;
        const float* w = (mat == 0) ? wq : ((mat == 1) ? wk : wv);
        const float* b = (mat == 0) ? bq : ((mat == 1) ? bk : bv);
        float* o       = (mat == 0) ? q  : ((mat == 1) ? k  : v);
        float acc[32];
#pragma unroll
        for (int j = 0; j < 32; j++) acc[j] = b[c0 + j];
        for (int kk = 0; kk < L; ++kk) {
            float xv = xrow[kk];
            const float* wr = w + kk * 128 + c0;  // wave-uniform -> s_load
#pragma unroll
            for (int j = 0; j < 32; j++) acc[j] = fmaf(xv, wr[j], acc[j]);
        }
        if (n < N) {
            float* op = o + (long)n * 128 + c0;
#pragma unroll
            for (int j = 0; j < 32; j += 4)
                *(float4*)(op + j) = make_float4(acc[j], acc[j+1], acc[j+2], acc[j+3]);
        }
    } else {
        float acc[32];
#pragma unroll
        for (int j = 0; j < 32; j++) acc[j] = bs[j];
        for (int kk = 0; kk < L; ++kk) {
            float xv = xrow[kk];
            const float* wr = ws + kk * 32;  // wave-uniform -> s_load
#pragma unroll
            for (int j = 0; j < 32; j++) acc[j] = fmaf(xv, wr[j], acc[j]);
        }
        if (n < N) {
            float* op = skip + (long)n * 32;
#pragma unroll
            for (int j = 0; j < 32; j += 4)
                *(float4*)(op + j) = make_float4(acc[j], acc[j+1], acc[j+2], acc[j+3]);
        }
    }
}

// ---------------- K2: fused per-node online-softmax attention + epilogue ----
// one wave per dst node; lane l owns dims {2l, 2l+1}; head = l>>4.
// epilogue: h = relu(head_mean + skip) (skip already includes bias).
__global__ __launch_bounds__(256) void attn_kernel(
    const float* __restrict__ q, const float* __restrict__ k,
    const float* __restrict__ v, const int* __restrict__ rowptr,
    const int* __restrict__ perm, const float* __restrict__ skip,
    float* __restrict__ h, int N)
{
    const int wid = (blockIdx.x * 256 + threadIdx.x) >> 6;
    const int lane = threadIdx.x & 63;
    if (wid >= N) return;
    const int d = wid;
    const float2 q2 = *(const float2*)(q + (long)d * 128 + lane * 2);
    float m = -INFINITY, den = 0.f;
    float ox = 0.f, oy = 0.f;
    const int beg = rowptr[d], end = rowptr[d + 1];
    const float scale = 0.17677669529663687f;  // 1/sqrt(32)
    int idx = beg;
    for (; idx + 1 < end; idx += 2) {
        int s0 = perm[idx], s1 = perm[idx + 1];
        const float2 k0 = *(const float2*)(k + (long)s0 * 128 + lane * 2);
        const float2 k1 = *(const float2*)(k + (long)s1 * 128 + lane * 2);
        const float2 v0 = *(const float2*)(v + (long)s0 * 128 + lane * 2);
        const float2 v1 = *(const float2*)(v + (long)s1 * 128 + lane * 2);
        float p0 = q2.x * k0.x + q2.y * k0.y;
        float p1 = q2.x * k1.x + q2.y * k1.y;
        p0 += __shfl_xor(p0, 1);  p1 += __shfl_xor(p1, 1);
        p0 += __shfl_xor(p0, 2);  p1 += __shfl_xor(p1, 2);
        p0 += __shfl_xor(p0, 4);  p1 += __shfl_xor(p1, 4);
        p0 += __shfl_xor(p0, 8);  p1 += __shfl_xor(p1, 8);
        float l0 = p0 * scale, l1 = p1 * scale;
        float nm = fmaxf(m, l0);
        float sc = __expf(m - nm);
        float w  = __expf(l0 - nm);
        den = den * sc + w;
        ox = ox * sc + w * v0.x;
        oy = oy * sc + w * v0.y;
        m = nm;
        nm = fmaxf(m, l1);
        sc = __expf(m - nm);
        w  = __expf(l1 - nm);
        den = den * sc + w;
        ox = ox * sc + w * v1.x;
        oy = oy * sc + w * v1.y;
        m = nm;
    }
    if (idx < end) {
        int s0 = perm[idx];
        const float2 k0 = *(const float2*)(k + (long)s0 * 128 + lane * 2);
        const float2 v0 = *(const float2*)(v + (long)s0 * 128 + lane * 2);
        float p0 = q2.x * k0.x + q2.y * k0.y;
        p0 += __shfl_xor(p0, 1);
        p0 += __shfl_xor(p0, 2);
        p0 += __shfl_xor(p0, 4);
        p0 += __shfl_xor(p0, 8);
        float l0 = p0 * scale;
        float nm = fmaxf(m, l0);
        float sc = __expf(m - nm);
        float w  = __expf(l0 - nm);
        den = den * sc + w;
        ox = ox * sc + w * v0.x;
        oy = oy * sc + w * v0.y;
    }
    float inv = 1.f / (den + 1e-16f);
    ox *= inv; oy *= inv;
    ox += __shfl_xor(ox, 16); oy += __shfl_xor(oy, 16);
    ox += __shfl_xor(ox, 32); oy += __shfl_xor(oy, 32);
    if (lane < 16) {
        float2 sk = *(const float2*)(skip + (long)d * 32 + lane * 2);
        float rx = 0.25f * ox + sk.x;
        float ry = 0.25f * oy + sk.y;
        float2 r = make_float2(rx > 0.f ? rx : 0.f, ry > 0.f ? ry : 0.f);
        *(float2*)(h + (long)d * 32 + lane * 2) = r;
    }
}

// ---------------- K3: final classifier [N,32] @ [32,40] + bc ----------------
__global__ __launch_bounds__(256) void classify_kernel(
    const float* __restrict__ h, const float* __restrict__ wc,
    const float* __restrict__ bc, float* __restrict__ out, int N)
{
    int gid = blockIdx.x * blockDim.x + threadIdx.x;
    if (gid >= N * 40) return;
    int n = gid / 40, o = gid - (gid / 40) * 40;
    float acc = bc[o];
    const float* hr = h + (long)n * 32;
#pragma unroll
    for (int l = 0; l < 32; ++l) acc += hr[l] * wc[l * 40 + o];
    out[gid] = acc;
}

extern "C" void kernel_launch(void* const* d_in, const int* in_sizes, int n_in,
                              void* d_out, int out_size, void* d_ws, size_t ws_size,
                              hipStream_t stream)
{
    const float* x   = (const float*)d_in[0];
    const int* ei    = (const int*)d_in[1];
    const float* wq1 = (const float*)d_in[2];  const float* bq1 = (const float*)d_in[3];
    const float* wk1 = (const float*)d_in[4];  const float* bk1 = (const float*)d_in[5];
    const float* wv1 = (const float*)d_in[6];  const float* bv1 = (const float*)d_in[7];
    const float* ws1 = (const float*)d_in[8];  const float* bs1 = (const float*)d_in[9];
    const float* wq2 = (const float*)d_in[10]; const float* bq2 = (const float*)d_in[11];
    const float* wk2 = (const float*)d_in[12]; const float* bk2 = (const float*)d_in[13];
    const float* wv2 = (const float*)d_in[14]; const float* bv2 = (const float*)d_in[15];
    const float* ws2 = (const float*)d_in[16]; const float* bs2 = (const float*)d_in[17];
    const float* wc  = (const float*)d_in[18]; const float* bc  = (const float*)d_in[19];

    const int N = in_sizes[0] / 128;   // 50000
    const int E = in_sizes[1] / 2;     // 800000
    const int* src = ei;
    const int* dst = ei + E;

    // workspace layout
    float* q    = (float*)d_ws;            // N*128
    float* k    = q + (long)N * 128;       // N*128
    float* v    = k + (long)N * 128;       // N*128
    float* skip = v + (long)N * 128;       // N*32
    float* h1   = skip + (long)N * 32;     // N*32
    float* h2   = h1 + (long)N * 32;       // N*32
    int* deg    = (int*)(h2 + (long)N * 32); // N
    int* rowptr = deg + N;                 // N+1
    int* cursor = rowptr + N + 1;          // N
    int* perm   = cursor + N;              // E

    const int projGrid = (N + 63) / 64;
    const int eGrid    = (E + 255) / 256;
    const int attnGrid = (N + 3) / 4;          // 4 waves/block

    // ---------------- CSR build (once; reused by both layers) ----------------
    hipMemsetAsync(deg, 0, (size_t)N * 4, stream);
    hist_kernel<<<eGrid, 256, 0, stream>>>(dst, deg, E);
    scan_kernel<<<1, 1024, 0, stream>>>(deg, rowptr, cursor, N);
    fill_kernel<<<eGrid, 256, 0, stream>>>(src, dst, cursor, perm, E);

    // ---------------- layer 1 ----------------
    proj_kernel<128><<<projGrid, 832, 0, stream>>>(x, wq1, bq1, wk1, bk1, wv1, bv1,
                                                   ws1, bs1, q, k, v, skip, N);
    attn_kernel<<<attnGrid, 256, 0, stream>>>(q, k, v, rowptr, perm, skip, h1, N);

    // ---------------- layer 2 ----------------
    proj_kernel<32><<<projGrid, 832, 0, stream>>>(h1, wq2, bq2, wk2, bk2, wv2, bv2,
                                                  ws2, bs2, q, k, v, skip, N);
    attn_kernel<<<attnGrid, 256, 0, stream>>>(q, k, v, rowptr, perm, skip, h2, N);

    // ---------------- classifier ----------------
    classify_kernel<<<(N * 40 + 255) / 256, 256, 0, stream>>>(h2, wc, bc, (float*)d_out, N);
}

// Round 6
// 516.950 us; speedup vs baseline: 1.3681x; 1.3681x over previous
//
#include <hip/hip_runtime.h>
#include <hip/hip_bf16.h>

typedef __attribute__((ext_vector_type(8))) short short8;       // 8 bf16 (A/B frag)
typedef __attribute__((ext_vector_type(4))) float floatx4;      // C/D frag
typedef __attribute__((ext_vector_type(4))) unsigned short ushort4v;

__device__ inline unsigned short f2bf(float x) {                 // RNE f32->bf16 bits
    unsigned int u = __float_as_uint(x);
    u += 0x7FFFu + ((u >> 16) & 1u);
    return (unsigned short)(u >> 16);
}
__device__ inline float bf2f(unsigned short h) {
    return __uint_as_float(((unsigned int)h) << 16);
}

// ---------------- CSR build ----------------
__global__ __launch_bounds__(256) void hist_kernel(
    const int* __restrict__ dst, int* __restrict__ deg, int E)
{
    int e = blockIdx.x * blockDim.x + threadIdx.x;
    if (e < E) atomicAdd(&deg[dst[e]], 1);
}

__global__ __launch_bounds__(1024) void scan_kernel(
    const int* __restrict__ deg, int* __restrict__ rowptr,
    int* __restrict__ cursor, int N)
{
    __shared__ int wsum[16];
    __shared__ int wpre[16];
    __shared__ int chunk_total;
    __shared__ int carry_s;
    const int tid = threadIdx.x, wave = tid >> 6, lane = tid & 63;
    if (tid == 0) carry_s = 0;
    __syncthreads();
    for (int base = 0; base < N; base += 1024) {
        int i = base + tid;
        int val = (i < N) ? deg[i] : 0;
        int inc = val;
#pragma unroll
        for (int off = 1; off < 64; off <<= 1) {
            int t = __shfl_up(inc, off, 64);
            if (lane >= off) inc += t;
        }
        if (lane == 63) wsum[wave] = inc;
        __syncthreads();
        if (wave == 0) {
            int s = (lane < 16) ? wsum[lane] : 0;
#pragma unroll
            for (int off = 1; off < 16; off <<= 1) {
                int t = __shfl_up(s, off, 64);
                if (lane >= off) s += t;
            }
            if (lane < 16) wpre[lane] = s - wsum[lane];
            if (lane == 15) chunk_total = s;
        }
        __syncthreads();
        int exc = carry_s + wpre[wave] + inc - val;
        if (i < N) { rowptr[i] = exc; cursor[i] = exc; }
        __syncthreads();
        if (tid == 0) carry_s += chunk_total;
        __syncthreads();
    }
    if (tid == 0) rowptr[N] = carry_s;
}

__global__ __launch_bounds__(256) void fill_kernel(
    const int* __restrict__ src, const int* __restrict__ dst,
    int* __restrict__ cursor, int* __restrict__ perm, int E)
{
    int e = blockIdx.x * blockDim.x + threadIdx.x;
    if (e >= E) return;
    int pos = atomicAdd(&cursor[dst[e]], 1);
    perm[pos] = src[e];
}

// ---------------- weight prep: Wt[col][k] hi/lo bf16 + bias concat ----------
// col 0..127 = wq, 128..255 = wk, 256..383 = wv, 384..415 = ws
template <int L>
__global__ void wprep_kernel(
    const float* __restrict__ wq, const float* __restrict__ bq,
    const float* __restrict__ wk, const float* __restrict__ bk,
    const float* __restrict__ wv, const float* __restrict__ bv,
    const float* __restrict__ ws, const float* __restrict__ bs,
    unsigned short* __restrict__ wt_hi, unsigned short* __restrict__ wt_lo,
    float* __restrict__ bias)
{
    int c = blockIdx.x;   // 0..415
    int t = threadIdx.x;  // 0..L-1
    const float* w; const float* b; int cc, ncols;
    if (c < 384) {
        int m = c >> 7; cc = c & 127; ncols = 128;
        w = (m == 0) ? wq : ((m == 1) ? wk : wv);
        b = (m == 0) ? bq : ((m == 1) ? bk : bv);
    } else {
        cc = c - 384; ncols = 32; w = ws; b = bs;
    }
    float val = w[t * ncols + cc];
    unsigned short h = f2bf(val);
    wt_hi[c * L + t] = h;
    wt_lo[c * L + t] = f2bf(val - bf2f(h));
    if (t == 0) bias[c] = b[cc];
}

// ---------------- K1: MFMA projection (split-bf16, near-f32 accurate) -------
// Block = 4 waves, 32 nodes. Wave w: node-subtile (w&1), col-tiles t=(w>>1),
// t+2, ... over 26 tiles of 16 cols (416 total = q|k|v|skip).
// A = Wt[col][k] (M=cols), B = X (N=nodes), C: col(lane&15)=node,
// row(quad*4+reg)=wcol -> float4/ushort4 stores.
template <int L>
__global__ __launch_bounds__(256) void proj_mfma(
    const float* __restrict__ xin,
    const unsigned short* __restrict__ wt_hi,
    const unsigned short* __restrict__ wt_lo,
    const float* __restrict__ bias,
    float* __restrict__ q, unsigned short* __restrict__ kv,
    float* __restrict__ skip, int N)
{
    constexpr int LP = L + 8;   // ushort pad: 16B-aligned rows, 2-way banks
    constexpr int KS = L / 32;
    __shared__ unsigned short xh[32 * LP];
    __shared__ unsigned short xl[32 * LP];
    const int tid = threadIdx.x, lane = tid & 63, w = tid >> 6;
    const int n0 = blockIdx.x * 32;

    // stage X as bf16 hi/lo
    for (int f = tid; f < 32 * (L / 4); f += 256) {
        int row = f / (L / 4);
        int k4 = (f - row * (L / 4)) * 4;
        int n = n0 + row;
        float4 xv = (n < N) ? *(const float4*)(xin + (long)n * L + k4)
                            : make_float4(0.f, 0.f, 0.f, 0.f);
        unsigned short h0 = f2bf(xv.x), h1 = f2bf(xv.y),
                       h2 = f2bf(xv.z), h3 = f2bf(xv.w);
        ushort4v hs = {h0, h1, h2, h3};
        ushort4v ls = {f2bf(xv.x - bf2f(h0)), f2bf(xv.y - bf2f(h1)),
                       f2bf(xv.z - bf2f(h2)), f2bf(xv.w - bf2f(h3))};
        *(ushort4v*)(xh + row * LP + k4) = hs;
        *(ushort4v*)(xl + row * LP + k4) = ls;
    }
    __syncthreads();

    const int li = lane & 15, quad = lane >> 4;
    const int sub = w & 1;
    const int node = n0 + sub * 16 + li;

    // B-frags (this wave's nodes), reused across all col-tiles
    short8 Bh[KS], Bl[KS];
#pragma unroll
    for (int ks = 0; ks < KS; ks++) {
        int off = (sub * 16 + li) * LP + ks * 32 + quad * 8;
        Bh[ks] = *(const short8*)(xh + off);
        Bl[ks] = *(const short8*)(xl + off);
    }

    for (int t = (w >> 1); t < 26; t += 2) {
        const int c0 = t * 16;
        floatx4 acc = {0.f, 0.f, 0.f, 0.f};
#pragma unroll
        for (int ks = 0; ks < KS; ks++) {
            long woff = (long)(c0 + li) * L + ks * 32 + quad * 8;
            short8 Ah = *(const short8*)(wt_hi + woff);
            short8 Al = *(const short8*)(wt_lo + woff);
            acc = __builtin_amdgcn_mfma_f32_16x16x32_bf16(Ah, Bh[ks], acc, 0, 0, 0);
            acc = __builtin_amdgcn_mfma_f32_16x16x32_bf16(Ah, Bl[ks], acc, 0, 0, 0);
            acc = __builtin_amdgcn_mfma_f32_16x16x32_bf16(Al, Bh[ks], acc, 0, 0, 0);
        }
        if (node < N) {
            int cg = c0 + quad * 4;  // global col of acc[0]
            float r0 = acc[0] + bias[cg + 0];
            float r1 = acc[1] + bias[cg + 1];
            float r2 = acc[2] + bias[cg + 2];
            float r3 = acc[3] + bias[cg + 3];
            if (cg < 128) {
                *(floatx4*)(q + (long)node * 128 + cg) = (floatx4){r0, r1, r2, r3};
            } else if (cg < 384) {
                ushort4v kvv = {f2bf(r0), f2bf(r1), f2bf(r2), f2bf(r3)};
                *(ushort4v*)(kv + (long)node * 256 + (cg - 128)) = kvv;
            } else {
                *(floatx4*)(skip + (long)node * 32 + (cg - 384)) = (floatx4){r0, r1, r2, r3};
            }
        }
    }
}

// ---------------- K2: fused per-node online-softmax attention + epilogue ----
// one wave per dst node; lane l owns dims {2l, 2l+1}; head = l>>4.
// kv packed bf16: k at [s*256 + c], v at [s*256 + 128 + c].
__global__ __launch_bounds__(256) void attn_kernel(
    const float* __restrict__ q, const unsigned short* __restrict__ kv,
    const int* __restrict__ rowptr, const int* __restrict__ perm,
    const float* __restrict__ skip, float* __restrict__ h, int N)
{
    const int wid = (blockIdx.x * 256 + threadIdx.x) >> 6;
    const int lane = threadIdx.x & 63;
    if (wid >= N) return;
    const int d = wid;
    const float2 q2 = *(const float2*)(q + (long)d * 128 + lane * 2);
    float m = -INFINITY, den = 0.f;
    float ox = 0.f, oy = 0.f;
    const int beg = rowptr[d], end = rowptr[d + 1];
    const float scale = 0.17677669529663687f;  // 1/sqrt(32)
    int idx = beg;
    for (; idx + 1 < end; idx += 2) {
        int s0 = perm[idx], s1 = perm[idx + 1];
        unsigned int kr0 = *(const unsigned int*)(kv + (long)s0 * 256 + lane * 2);
        unsigned int vr0 = *(const unsigned int*)(kv + (long)s0 * 256 + 128 + lane * 2);
        unsigned int kr1 = *(const unsigned int*)(kv + (long)s1 * 256 + lane * 2);
        unsigned int vr1 = *(const unsigned int*)(kv + (long)s1 * 256 + 128 + lane * 2);
        float k0x = __uint_as_float(kr0 << 16), k0y = __uint_as_float(kr0 & 0xFFFF0000u);
        float k1x = __uint_as_float(kr1 << 16), k1y = __uint_as_float(kr1 & 0xFFFF0000u);
        float p0 = q2.x * k0x + q2.y * k0y;
        float p1 = q2.x * k1x + q2.y * k1y;
        p0 += __shfl_xor(p0, 1);  p1 += __shfl_xor(p1, 1);
        p0 += __shfl_xor(p0, 2);  p1 += __shfl_xor(p1, 2);
        p0 += __shfl_xor(p0, 4);  p1 += __shfl_xor(p1, 4);
        p0 += __shfl_xor(p0, 8);  p1 += __shfl_xor(p1, 8);
        float l0 = p0 * scale, l1 = p1 * scale;
        float v0x = __uint_as_float(vr0 << 16), v0y = __uint_as_float(vr0 & 0xFFFF0000u);
        float v1x = __uint_as_float(vr1 << 16), v1y = __uint_as_float(vr1 & 0xFFFF0000u);
        float nm = fmaxf(m, l0);
        float sc = __expf(m - nm);
        float wt = __expf(l0 - nm);
        den = den * sc + wt;
        ox = ox * sc + wt * v0x;
        oy = oy * sc + wt * v0y;
        m = nm;
        nm = fmaxf(m, l1);
        sc = __expf(m - nm);
        wt = __expf(l1 - nm);
        den = den * sc + wt;
        ox = ox * sc + wt * v1x;
        oy = oy * sc + wt * v1y;
        m = nm;
    }
    if (idx < end) {
        int s0 = perm[idx];
        unsigned int kr0 = *(const unsigned int*)(kv + (long)s0 * 256 + lane * 2);
        unsigned int vr0 = *(const unsigned int*)(kv + (long)s0 * 256 + 128 + lane * 2);
        float k0x = __uint_as_float(kr0 << 16), k0y = __uint_as_float(kr0 & 0xFFFF0000u);
        float p0 = q2.x * k0x + q2.y * k0y;
        p0 += __shfl_xor(p0, 1);
        p0 += __shfl_xor(p0, 2);
        p0 += __shfl_xor(p0, 4);
        p0 += __shfl_xor(p0, 8);
        float l0 = p0 * scale;
        float v0x = __uint_as_float(vr0 << 16), v0y = __uint_as_float(vr0 & 0xFFFF0000u);
        float nm = fmaxf(m, l0);
        float sc = __expf(m - nm);
        float wt = __expf(l0 - nm);
        den = den * sc + wt;
        ox = ox * sc + wt * v0x;
        oy = oy * sc + wt * v0y;
    }
    float inv = 1.f / (den + 1e-16f);
    ox *= inv; oy *= inv;
    ox += __shfl_xor(ox, 16); oy += __shfl_xor(oy, 16);
    ox += __shfl_xor(ox, 32); oy += __shfl_xor(oy, 32);
    if (lane < 16) {
        float2 sk = *(const float2*)(skip + (long)d * 32 + lane * 2);
        float rx = 0.25f * ox + sk.x;
        float ry = 0.25f * oy + sk.y;
        float2 r = make_float2(rx > 0.f ? rx : 0.f, ry > 0.f ? ry : 0.f);
        *(float2*)(h + (long)d * 32 + lane * 2) = r;
    }
}

// ---------------- K3: final classifier [N,32] @ [32,40] + bc ----------------
__global__ __launch_bounds__(256) void classify_kernel(
    const float* __restrict__ h, const float* __restrict__ wc,
    const float* __restrict__ bc, float* __restrict__ out, int N)
{
    int gid = blockIdx.x * blockDim.x + threadIdx.x;
    if (gid >= N * 40) return;
    int n = gid / 40, o = gid - (gid / 40) * 40;
    float acc = bc[o];
    const float* hr = h + (long)n * 32;
#pragma unroll
    for (int l = 0; l < 32; ++l) acc += hr[l] * wc[l * 40 + o];
    out[gid] = acc;
}

extern "C" void kernel_launch(void* const* d_in, const int* in_sizes, int n_in,
                              void* d_out, int out_size, void* d_ws, size_t ws_size,
                              hipStream_t stream)
{
    const float* x   = (const float*)d_in[0];
    const int* ei    = (const int*)d_in[1];
    const float* wq1 = (const float*)d_in[2];  const float* bq1 = (const float*)d_in[3];
    const float* wk1 = (const float*)d_in[4];  const float* bk1 = (const float*)d_in[5];
    const float* wv1 = (const float*)d_in[6];  const float* bv1 = (const float*)d_in[7];
    const float* ws1 = (const float*)d_in[8];  const float* bs1 = (const float*)d_in[9];
    const float* wq2 = (const float*)d_in[10]; const float* bq2 = (const float*)d_in[11];
    const float* wk2 = (const float*)d_in[12]; const float* bk2 = (const float*)d_in[13];
    const float* wv2 = (const float*)d_in[14]; const float* bv2 = (const float*)d_in[15];
    const float* ws2 = (const float*)d_in[16]; const float* bs2 = (const float*)d_in[17];
    const float* wc  = (const float*)d_in[18]; const float* bc  = (const float*)d_in[19];

    const int N = in_sizes[0] / 128;   // 50000
    const int E = in_sizes[1] / 2;     // 800000
    const int* src = ei;
    const int* dst = ei + E;

    // workspace layout (bytes, 256-aligned chunks)
    char* p = (char*)d_ws;
    auto take = [&](size_t bytes) { char* r = p; p += (bytes + 255) & ~(size_t)255; return r; };
    float* q            = (float*)take((size_t)N * 128 * 4);
    unsigned short* kv  = (unsigned short*)take((size_t)N * 256 * 2);
    float* skip         = (float*)take((size_t)N * 32 * 4);
    float* h1           = (float*)take((size_t)N * 32 * 4);
    float* h2           = (float*)take((size_t)N * 32 * 4);
    unsigned short* wt1h = (unsigned short*)take(416 * 128 * 2);
    unsigned short* wt1l = (unsigned short*)take(416 * 128 * 2);
    unsigned short* wt2h = (unsigned short*)take(416 * 32 * 2);
    unsigned short* wt2l = (unsigned short*)take(416 * 32 * 2);
    float* bias1        = (float*)take(416 * 4);
    float* bias2        = (float*)take(416 * 4);
    int* deg            = (int*)take((size_t)N * 4);
    int* rowptr         = (int*)take((size_t)(N + 1) * 4);
    int* cursor         = (int*)take((size_t)N * 4);
    int* perm           = (int*)take((size_t)E * 4);

    const int projGrid = (N + 31) / 32;
    const int eGrid    = (E + 255) / 256;
    const int attnGrid = (N + 3) / 4;          // 4 waves/block

    // ---------------- weight prep + CSR build ----------------
    wprep_kernel<128><<<416, 128, 0, stream>>>(wq1, bq1, wk1, bk1, wv1, bv1,
                                               ws1, bs1, wt1h, wt1l, bias1);
    wprep_kernel<32><<<416, 32, 0, stream>>>(wq2, bq2, wk2, bk2, wv2, bv2,
                                             ws2, bs2, wt2h, wt2l, bias2);
    hipMemsetAsync(deg, 0, (size_t)N * 4, stream);
    hist_kernel<<<eGrid, 256, 0, stream>>>(dst, deg, E);
    scan_kernel<<<1, 1024, 0, stream>>>(deg, rowptr, cursor, N);
    fill_kernel<<<eGrid, 256, 0, stream>>>(src, dst, cursor, perm, E);

    // ---------------- layer 1 ----------------
    proj_mfma<128><<<projGrid, 256, 0, stream>>>(x, wt1h, wt1l, bias1, q, kv, skip, N);
    attn_kernel<<<attnGrid, 256, 0, stream>>>(q, kv, rowptr, perm, skip, h1, N);

    // ---------------- layer 2 ----------------
    proj_mfma<32><<<projGrid, 256, 0, stream>>>(h1, wt2h, wt2l, bias2, q, kv, skip, N);
    attn_kernel<<<attnGrid, 256, 0, stream>>>(q, kv, rowptr, perm, skip, h2, N);

    // ---------------- classifier ----------------
    classify_kernel<<<(N * 40 + 255) / 256, 256, 0, stream>>>(h2, wc, bc, (float*)d_out, N);
}

// Round 7
// 499.668 us; speedup vs baseline: 1.4154x; 1.0346x over previous
//
#include <hip/hip_runtime.h>
#include <hip/hip_bf16.h>

typedef __attribute__((ext_vector_type(8))) short short8;       // 8 bf16 (A/B frag)
typedef __attribute__((ext_vector_type(4))) float floatx4;      // C/D frag
typedef __attribute__((ext_vector_type(4))) unsigned short ushort4v;

__device__ inline unsigned short f2bf(float x) {                 // RNE f32->bf16 bits
    unsigned int u = __float_as_uint(x);
    u += 0x7FFFu + ((u >> 16) & 1u);
    return (unsigned short)(u >> 16);
}
__device__ inline float bf2f(unsigned short h) {
    return __uint_as_float(((unsigned int)h) << 16);
}

// ---------------- CSR build ----------------
__global__ __launch_bounds__(256) void hist_kernel(
    const int* __restrict__ dst, int* __restrict__ deg, int E)
{
    int e = blockIdx.x * blockDim.x + threadIdx.x;
    if (e < E) atomicAdd(&deg[dst[e]], 1);
}

__global__ __launch_bounds__(1024) void scan_kernel(
    const int* __restrict__ deg, int* __restrict__ rowptr,
    int* __restrict__ cursor, int N)
{
    __shared__ int wsum[16];
    __shared__ int wpre[16];
    __shared__ int chunk_total;
    __shared__ int carry_s;
    const int tid = threadIdx.x, wave = tid >> 6, lane = tid & 63;
    if (tid == 0) carry_s = 0;
    __syncthreads();
    for (int base = 0; base < N; base += 1024) {
        int i = base + tid;
        int val = (i < N) ? deg[i] : 0;
        int inc = val;
#pragma unroll
        for (int off = 1; off < 64; off <<= 1) {
            int t = __shfl_up(inc, off, 64);
            if (lane >= off) inc += t;
        }
        if (lane == 63) wsum[wave] = inc;
        __syncthreads();
        if (wave == 0) {
            int s = (lane < 16) ? wsum[lane] : 0;
#pragma unroll
            for (int off = 1; off < 16; off <<= 1) {
                int t = __shfl_up(s, off, 64);
                if (lane >= off) s += t;
            }
            if (lane < 16) wpre[lane] = s - wsum[lane];
            if (lane == 15) chunk_total = s;
        }
        __syncthreads();
        int exc = carry_s + wpre[wave] + inc - val;
        if (i < N) { rowptr[i] = exc; cursor[i] = exc; }
        __syncthreads();
        if (tid == 0) carry_s += chunk_total;
        __syncthreads();
    }
    if (tid == 0) rowptr[N] = carry_s;
}

__global__ __launch_bounds__(256) void fill_kernel(
    const int* __restrict__ src, const int* __restrict__ dst,
    int* __restrict__ cursor, int* __restrict__ perm, int E)
{
    int e = blockIdx.x * blockDim.x + threadIdx.x;
    if (e >= E) return;
    int pos = atomicAdd(&cursor[dst[e]], 1);
    perm[pos] = src[e];
}

// ---------------- weight prep: Wt[col][k] hi/lo bf16 + bias concat ----------
// col 0..127 = wq, 128..255 = wk, 256..383 = wv, 384..415 = ws
template <int L>
__global__ void wprep_kernel(
    const float* __restrict__ wq, const float* __restrict__ bq,
    const float* __restrict__ wk, const float* __restrict__ bk,
    const float* __restrict__ wv, const float* __restrict__ bv,
    const float* __restrict__ ws, const float* __restrict__ bs,
    unsigned short* __restrict__ wt_hi, unsigned short* __restrict__ wt_lo,
    float* __restrict__ bias)
{
    int c = blockIdx.x;   // 0..415
    int t = threadIdx.x;  // 0..L-1
    const float* w; const float* b; int cc, ncols;
    if (c < 384) {
        int m = c >> 7; cc = c & 127; ncols = 128;
        w = (m == 0) ? wq : ((m == 1) ? wk : wv);
        b = (m == 0) ? bq : ((m == 1) ? bk : bv);
    } else {
        cc = c - 384; ncols = 32; w = ws; b = bs;
    }
    float val = w[t * ncols + cc];
    unsigned short h = f2bf(val);
    wt_hi[c * L + t] = h;
    wt_lo[c * L + t] = f2bf(val - bf2f(h));
    if (t == 0) bias[c] = b[cc];
}

// ---------------- proj helpers ----------------
template <int KS, int L>
__device__ __forceinline__ void load_tile(
    const unsigned short* __restrict__ hi, const unsigned short* __restrict__ lo,
    int t, int li, int quad, short8* Ah, short8* Al)
{
#pragma unroll
    for (int ks = 0; ks < KS; ks++) {
        long woff = (long)(t * 16 + li) * L + ks * 32 + quad * 8;
        Ah[ks] = *(const short8*)(hi + woff);
        Al[ks] = *(const short8*)(lo + woff);
    }
}

template <int KS>
__device__ __forceinline__ floatx4 tile_mfma(
    const short8* Ah, const short8* Al, const short8* Bh, const short8* Bl)
{
    floatx4 acc = {0.f, 0.f, 0.f, 0.f};
#pragma unroll
    for (int ks = 0; ks < KS; ks++) {
        acc = __builtin_amdgcn_mfma_f32_16x16x32_bf16(Ah[ks], Bh[ks], acc, 0, 0, 0);
        acc = __builtin_amdgcn_mfma_f32_16x16x32_bf16(Ah[ks], Bl[ks], acc, 0, 0, 0);
        acc = __builtin_amdgcn_mfma_f32_16x16x32_bf16(Al[ks], Bh[ks], acc, 0, 0, 0);
    }
    return acc;
}

// epilogue: tile t, acc -> q (f32) | kvp (interleaved bf16) | skip (f32)
__device__ __forceinline__ void store_tile(
    int t, int quad, int node, floatx4 acc, const float* __restrict__ bias,
    float* __restrict__ q, unsigned short* __restrict__ kvp,
    float* __restrict__ skip)
{
    int cg = t * 16 + quad * 4;
    float r0 = acc[0] + bias[cg + 0];
    float r1 = acc[1] + bias[cg + 1];
    float r2 = acc[2] + bias[cg + 2];
    float r3 = acc[3] + bias[cg + 3];
    if (cg < 128) {
        *(floatx4*)(q + (long)node * 128 + cg) = (floatx4){r0, r1, r2, r3};
    } else if (cg < 384) {
        bool isV = cg >= 256;
        int d0 = cg - (isV ? 256 : 128);          // even, 0..124
        unsigned int p0 = (unsigned int)f2bf(r0) | ((unsigned int)f2bf(r1) << 16);
        unsigned int p1 = (unsigned int)f2bf(r2) | ((unsigned int)f2bf(r3) << 16);
        // lane j layout: [k_{2j}, k_{2j+1}, v_{2j}, v_{2j+1}]
        unsigned int* base = (unsigned int*)(kvp + (long)node * 256 + (d0 >> 1) * 4 + (isV ? 2 : 0));
        base[0] = p0;
        base[2] = p1;
    } else {
        *(floatx4*)(skip + (long)node * 32 + (cg - 384)) = (floatx4){r0, r1, r2, r3};
    }
}

// ---------------- K1: MFMA projection (split-bf16, pipelined) ----------------
// Block = 4 waves, 32 nodes. Wave w: node-subtile (w&1), tiles t0=(w>>1)+2j,
// j=0..12 (26 tiles of 16 cols = q|k|v|skip). B-frags register-resident.
// L=128: double-buffered A prefetch. L=32: all 13 tiles' A preloaded.
template <int L>
__global__ __launch_bounds__(256) void proj_mfma(
    const float* __restrict__ xin,
    const unsigned short* __restrict__ wt_hi,
    const unsigned short* __restrict__ wt_lo,
    const float* __restrict__ bias,
    float* __restrict__ q, unsigned short* __restrict__ kvp,
    float* __restrict__ skip, int N)
{
    constexpr int LP = L + 8;   // ushort pad
    constexpr int KS = L / 32;
    __shared__ unsigned short xh[32 * LP];
    __shared__ unsigned short xl[32 * LP];
    const int tid = threadIdx.x, lane = tid & 63, w = tid >> 6;
    const int n0 = blockIdx.x * 32;

    // stage X as bf16 hi/lo
    for (int f = tid; f < 32 * (L / 4); f += 256) {
        int row = f / (L / 4);
        int k4 = (f - row * (L / 4)) * 4;
        int n = n0 + row;
        float4 xv = (n < N) ? *(const float4*)(xin + (long)n * L + k4)
                            : make_float4(0.f, 0.f, 0.f, 0.f);
        unsigned short h0 = f2bf(xv.x), h1 = f2bf(xv.y),
                       h2 = f2bf(xv.z), h3 = f2bf(xv.w);
        ushort4v hs = {h0, h1, h2, h3};
        ushort4v ls = {f2bf(xv.x - bf2f(h0)), f2bf(xv.y - bf2f(h1)),
                       f2bf(xv.z - bf2f(h2)), f2bf(xv.w - bf2f(h3))};
        *(ushort4v*)(xh + row * LP + k4) = hs;
        *(ushort4v*)(xl + row * LP + k4) = ls;
    }
    __syncthreads();

    const int li = lane & 15, quad = lane >> 4;
    const int sub = w & 1;
    const int node = n0 + sub * 16 + li;
    const bool valid = node < N;
    const int t0 = w >> 1;

    // B-frags (this wave's nodes), reused across all col-tiles
    short8 Bh[KS], Bl[KS];
#pragma unroll
    for (int ks = 0; ks < KS; ks++) {
        int off = (sub * 16 + li) * LP + ks * 32 + quad * 8;
        Bh[ks] = *(const short8*)(xh + off);
        Bl[ks] = *(const short8*)(xl + off);
    }

    if (KS == 1) {
        // L=32: preload ALL 13 tiles (26 loads in flight), then compute.
        short8 AhT[13], AlT[13];
#pragma unroll
        for (int j = 0; j < 13; j++)
            load_tile<KS, L>(wt_hi, wt_lo, t0 + 2 * j, li, quad, &AhT[j], &AlT[j]);
#pragma unroll
        for (int j = 0; j < 13; j++) {
            floatx4 acc = tile_mfma<KS>(&AhT[j], &AlT[j], Bh, Bl);
            if (valid) store_tile(t0 + 2 * j, quad, node, acc, bias, q, kvp, skip);
        }
    } else {
        // L=128: explicit double-buffered A prefetch.
        short8 Ah0[KS], Al0[KS], Ah1[KS], Al1[KS];
        load_tile<KS, L>(wt_hi, wt_lo, t0, li, quad, Ah0, Al0);
#pragma unroll
        for (int j = 0; j < 13; j++) {
            int t = t0 + 2 * j;
            if ((j & 1) == 0) {
                if (j < 12)
                    load_tile<KS, L>(wt_hi, wt_lo, t0 + 2 * (j + 1), li, quad, Ah1, Al1);
                floatx4 acc = tile_mfma<KS>(Ah0, Al0, Bh, Bl);
                if (valid) store_tile(t, quad, node, acc, bias, q, kvp, skip);
            } else {
                if (j < 12)
                    load_tile<KS, L>(wt_hi, wt_lo, t0 + 2 * (j + 1), li, quad, Ah0, Al0);
                floatx4 acc = tile_mfma<KS>(Ah1, Al1, Bh, Bl);
                if (valid) store_tile(t, quad, node, acc, bias, q, kvp, skip);
            }
        }
    }
}

// ---------------- K2: fused per-node online-softmax attention + epilogue ----
// one wave per dst node; lane l owns dims {2l, 2l+1}; head = l>>4.
// kvp interleaved bf16 per lane: [k_{2l},k_{2l+1},v_{2l},v_{2l+1}] (8 B).
__global__ __launch_bounds__(256) void attn_kernel(
    const float* __restrict__ q, const unsigned short* __restrict__ kvp,
    const int* __restrict__ rowptr, const int* __restrict__ perm,
    const float* __restrict__ skip, float* __restrict__ h, int N)
{
    const int wid = (blockIdx.x * 256 + threadIdx.x) >> 6;
    const int lane = threadIdx.x & 63;
    if (wid >= N) return;
    const int d = __builtin_amdgcn_readfirstlane(wid);  // uniform -> scalar loads
    const float2 q2 = *(const float2*)(q + (long)d * 128 + lane * 2);
    float m = -INFINITY, den = 0.f;
    float ox = 0.f, oy = 0.f;
    const int beg = rowptr[d], end = rowptr[d + 1];
    const float scale = 0.17677669529663687f;  // 1/sqrt(32)
    int idx = beg;
    for (; idx + 3 < end; idx += 4) {
        int s0 = perm[idx], s1 = perm[idx + 1], s2 = perm[idx + 2], s3 = perm[idx + 3];
        uint2 a0 = *(const uint2*)(kvp + (long)s0 * 256 + lane * 4);
        uint2 a1 = *(const uint2*)(kvp + (long)s1 * 256 + lane * 4);
        uint2 a2 = *(const uint2*)(kvp + (long)s2 * 256 + lane * 4);
        uint2 a3 = *(const uint2*)(kvp + (long)s3 * 256 + lane * 4);
        float p0 = q2.x * __uint_as_float(a0.x << 16) + q2.y * __uint_as_float(a0.x & 0xFFFF0000u);
        float p1 = q2.x * __uint_as_float(a1.x << 16) + q2.y * __uint_as_float(a1.x & 0xFFFF0000u);
        float p2 = q2.x * __uint_as_float(a2.x << 16) + q2.y * __uint_as_float(a2.x & 0xFFFF0000u);
        float p3 = q2.x * __uint_as_float(a3.x << 16) + q2.y * __uint_as_float(a3.x & 0xFFFF0000u);
        p0 += __shfl_xor(p0, 1);  p1 += __shfl_xor(p1, 1);  p2 += __shfl_xor(p2, 1);  p3 += __shfl_xor(p3, 1);
        p0 += __shfl_xor(p0, 2);  p1 += __shfl_xor(p1, 2);  p2 += __shfl_xor(p2, 2);  p3 += __shfl_xor(p3, 2);
        p0 += __shfl_xor(p0, 4);  p1 += __shfl_xor(p1, 4);  p2 += __shfl_xor(p2, 4);  p3 += __shfl_xor(p3, 4);
        p0 += __shfl_xor(p0, 8);  p1 += __shfl_xor(p1, 8);  p2 += __shfl_xor(p2, 8);  p3 += __shfl_xor(p3, 8);
        float l0 = p0 * scale, l1 = p1 * scale, l2 = p2 * scale, l3 = p3 * scale;
        float mb = fmaxf(fmaxf(l0, l1), fmaxf(l2, l3));
        float nm = fmaxf(m, mb);
        float sc = __expf(m - nm);
        float w0 = __expf(l0 - nm), w1 = __expf(l1 - nm),
              w2 = __expf(l2 - nm), w3 = __expf(l3 - nm);
        den = den * sc + ((w0 + w1) + (w2 + w3));
        float vx = w0 * __uint_as_float(a0.y << 16) + w1 * __uint_as_float(a1.y << 16)
                 + w2 * __uint_as_float(a2.y << 16) + w3 * __uint_as_float(a3.y << 16);
        float vy = w0 * __uint_as_float(a0.y & 0xFFFF0000u) + w1 * __uint_as_float(a1.y & 0xFFFF0000u)
                 + w2 * __uint_as_float(a2.y & 0xFFFF0000u) + w3 * __uint_as_float(a3.y & 0xFFFF0000u);
        ox = ox * sc + vx;
        oy = oy * sc + vy;
        m = nm;
    }
    for (; idx < end; idx++) {
        int s0 = perm[idx];
        uint2 a0 = *(const uint2*)(kvp + (long)s0 * 256 + lane * 4);
        float p0 = q2.x * __uint_as_float(a0.x << 16) + q2.y * __uint_as_float(a0.x & 0xFFFF0000u);
        p0 += __shfl_xor(p0, 1);
        p0 += __shfl_xor(p0, 2);
        p0 += __shfl_xor(p0, 4);
        p0 += __shfl_xor(p0, 8);
        float l0 = p0 * scale;
        float nm = fmaxf(m, l0);
        float sc = __expf(m - nm);
        float wt = __expf(l0 - nm);
        den = den * sc + wt;
        ox = ox * sc + wt * __uint_as_float(a0.y << 16);
        oy = oy * sc + wt * __uint_as_float(a0.y & 0xFFFF0000u);
        m = nm;
    }
    float inv = 1.f / (den + 1e-16f);
    ox *= inv; oy *= inv;
    ox += __shfl_xor(ox, 16); oy += __shfl_xor(oy, 16);
    ox += __shfl_xor(ox, 32); oy += __shfl_xor(oy, 32);
    if (lane < 16) {
        float2 sk = *(const float2*)(skip + (long)d * 32 + lane * 2);
        float rx = 0.25f * ox + sk.x;
        float ry = 0.25f * oy + sk.y;
        float2 r = make_float2(rx > 0.f ? rx : 0.f, ry > 0.f ? ry : 0.f);
        *(float2*)(h + (long)d * 32 + lane * 2) = r;
    }
}

// ---------------- K3: final classifier [N,32] @ [32,40] + bc ----------------
__global__ __launch_bounds__(256) void classify_kernel(
    const float* __restrict__ h, const float* __restrict__ wc,
    const float* __restrict__ bc, float* __restrict__ out, int N)
{
    int gid = blockIdx.x * blockDim.x + threadIdx.x;
    if (gid >= N * 40) return;
    int n = gid / 40, o = gid - (gid / 40) * 40;
    float acc = bc[o];
    const float* hr = h + (long)n * 32;
#pragma unroll
    for (int l = 0; l < 32; ++l) acc += hr[l] * wc[l * 40 + o];
    out[gid] = acc;
}

extern "C" void kernel_launch(void* const* d_in, const int* in_sizes, int n_in,
                              void* d_out, int out_size, void* d_ws, size_t ws_size,
                              hipStream_t stream)
{
    const float* x   = (const float*)d_in[0];
    const int* ei    = (const int*)d_in[1];
    const float* wq1 = (const float*)d_in[2];  const float* bq1 = (const float*)d_in[3];
    const float* wk1 = (const float*)d_in[4];  const float* bk1 = (const float*)d_in[5];
    const float* wv1 = (const float*)d_in[6];  const float* bv1 = (const float*)d_in[7];
    const float* ws1 = (const float*)d_in[8];  const float* bs1 = (const float*)d_in[9];
    const float* wq2 = (const float*)d_in[10]; const float* bq2 = (const float*)d_in[11];
    const float* wk2 = (const float*)d_in[12]; const float* bk2 = (const float*)d_in[13];
    const float* wv2 = (const float*)d_in[14]; const float* bv2 = (const float*)d_in[15];
    const float* ws2 = (const float*)d_in[16]; const float* bs2 = (const float*)d_in[17];
    const float* wc  = (const float*)d_in[18]; const float* bc  = (const float*)d_in[19];

    const int N = in_sizes[0] / 128;   // 50000
    const int E = in_sizes[1] / 2;     // 800000
    const int* src = ei;
    const int* dst = ei + E;

    // workspace layout (bytes, 256-aligned chunks)
    char* p = (char*)d_ws;
    auto take = [&](size_t bytes) { char* r = p; p += (bytes + 255) & ~(size_t)255; return r; };
    float* q             = (float*)take((size_t)N * 128 * 4);
    unsigned short* kvp  = (unsigned short*)take((size_t)N * 256 * 2);
    float* skip          = (float*)take((size_t)N * 32 * 4);
    float* h1            = (float*)take((size_t)N * 32 * 4);
    float* h2            = (float*)take((size_t)N * 32 * 4);
    unsigned short* wt1h = (unsigned short*)take(416 * 128 * 2);
    unsigned short* wt1l = (unsigned short*)take(416 * 128 * 2);
    unsigned short* wt2h = (unsigned short*)take(416 * 32 * 2);
    unsigned short* wt2l = (unsigned short*)take(416 * 32 * 2);
    float* bias1         = (float*)take(416 * 4);
    float* bias2         = (float*)take(416 * 4);
    int* deg             = (int*)take((size_t)N * 4);
    int* rowptr          = (int*)take((size_t)(N + 1) * 4);
    int* cursor          = (int*)take((size_t)N * 4);
    int* perm            = (int*)take((size_t)E * 4);

    const int projGrid = (N + 31) / 32;
    const int eGrid    = (E + 255) / 256;
    const int attnGrid = (N + 3) / 4;          // 4 waves/block

    // ---------------- weight prep + CSR build ----------------
    wprep_kernel<128><<<416, 128, 0, stream>>>(wq1, bq1, wk1, bk1, wv1, bv1,
                                               ws1, bs1, wt1h, wt1l, bias1);
    wprep_kernel<32><<<416, 32, 0, stream>>>(wq2, bq2, wk2, bk2, wv2, bv2,
                                             ws2, bs2, wt2h, wt2l, bias2);
    hipMemsetAsync(deg, 0, (size_t)N * 4, stream);
    hist_kernel<<<eGrid, 256, 0, stream>>>(dst, deg, E);
    scan_kernel<<<1, 1024, 0, stream>>>(deg, rowptr, cursor, N);
    fill_kernel<<<eGrid, 256, 0, stream>>>(src, dst, cursor, perm, E);

    // ---------------- layer 1 ----------------
    proj_mfma<128><<<projGrid, 256, 0, stream>>>(x, wt1h, wt1l, bias1, q, kvp, skip, N);
    attn_kernel<<<attnGrid, 256, 0, stream>>>(q, kvp, rowptr, perm, skip, h1, N);

    // ---------------- layer 2 ----------------
    proj_mfma<32><<<projGrid, 256, 0, stream>>>(h1, wt2h, wt2l, bias2, q, kvp, skip, N);
    attn_kernel<<<attnGrid, 256, 0, stream>>>(q, kvp, rowptr, perm, skip, h2, N);

    // ---------------- classifier ----------------
    classify_kernel<<<(N * 40 + 255) / 256, 256, 0, stream>>>(h2, wc, bc, (float*)d_out, N);
}

// Round 8
// 458.677 us; speedup vs baseline: 1.5419x; 1.0894x over previous
//
#include <hip/hip_runtime.h>
#include <hip/hip_bf16.h>

typedef __attribute__((ext_vector_type(8))) short short8;       // 8 bf16 (A/B frag)
typedef __attribute__((ext_vector_type(4))) float floatx4;      // C/D frag
typedef __attribute__((ext_vector_type(4))) unsigned short ushort4v;

__device__ inline unsigned short f2bf(float x) {                 // RNE f32->bf16 bits
    unsigned int u = __float_as_uint(x);
    u += 0x7FFFu + ((u >> 16) & 1u);
    return (unsigned short)(u >> 16);
}
__device__ inline float bf2f(unsigned short h) {
    return __uint_as_float(((unsigned int)h) << 16);
}

// ---------------- CSR build ----------------
__global__ __launch_bounds__(256) void hist_kernel(
    const int* __restrict__ dst, int* __restrict__ deg, int E)
{
    int e = blockIdx.x * blockDim.x + threadIdx.x;
    if (e < E) atomicAdd(&deg[dst[e]], 1);
}

__global__ __launch_bounds__(1024) void scan_kernel(
    const int* __restrict__ deg, int* __restrict__ rowptr,
    int* __restrict__ cursor, int N)
{
    __shared__ int wsum[16];
    __shared__ int wpre[16];
    __shared__ int chunk_total;
    __shared__ int carry_s;
    const int tid = threadIdx.x, wave = tid >> 6, lane = tid & 63;
    if (tid == 0) carry_s = 0;
    __syncthreads();
    for (int base = 0; base < N; base += 1024) {
        int i = base + tid;
        int val = (i < N) ? deg[i] : 0;
        int inc = val;
#pragma unroll
        for (int off = 1; off < 64; off <<= 1) {
            int t = __shfl_up(inc, off, 64);
            if (lane >= off) inc += t;
        }
        if (lane == 63) wsum[wave] = inc;
        __syncthreads();
        if (wave == 0) {
            int s = (lane < 16) ? wsum[lane] : 0;
#pragma unroll
            for (int off = 1; off < 16; off <<= 1) {
                int t = __shfl_up(s, off, 64);
                if (lane >= off) s += t;
            }
            if (lane < 16) wpre[lane] = s - wsum[lane];
            if (lane == 15) chunk_total = s;
        }
        __syncthreads();
        int exc = carry_s + wpre[wave] + inc - val;
        if (i < N) { rowptr[i] = exc; cursor[i] = exc; }
        __syncthreads();
        if (tid == 0) carry_s += chunk_total;
        __syncthreads();
    }
    if (tid == 0) rowptr[N] = carry_s;
}

__global__ __launch_bounds__(256) void fill_kernel(
    const int* __restrict__ src, const int* __restrict__ dst,
    int* __restrict__ cursor, int* __restrict__ perm, int E)
{
    int e = blockIdx.x * blockDim.x + threadIdx.x;
    if (e >= E) return;
    int pos = atomicAdd(&cursor[dst[e]], 1);
    perm[pos] = src[e];
}

// ---------------- weight prep: Wt[col][k] hi/lo bf16 + bias concat ----------
// col 0..127 = wq, 128..255 = wk, 256..383 = wv, 384..415 = ws
template <int L>
__global__ void wprep_kernel(
    const float* __restrict__ wq, const float* __restrict__ bq,
    const float* __restrict__ wk, const float* __restrict__ bk,
    const float* __restrict__ wv, const float* __restrict__ bv,
    const float* __restrict__ ws, const float* __restrict__ bs,
    unsigned short* __restrict__ wt_hi, unsigned short* __restrict__ wt_lo,
    float* __restrict__ bias)
{
    int c = blockIdx.x;   // 0..415
    int t = threadIdx.x;  // 0..L-1
    const float* w; const float* b; int cc, ncols;
    if (c < 384) {
        int m = c >> 7; cc = c & 127; ncols = 128;
        w = (m == 0) ? wq : ((m == 1) ? wk : wv);
        b = (m == 0) ? bq : ((m == 1) ? bk : bv);
    } else {
        cc = c - 384; ncols = 32; w = ws; b = bs;
    }
    float val = w[t * ncols + cc];
    unsigned short h = f2bf(val);
    wt_hi[c * L + t] = h;
    wt_lo[c * L + t] = f2bf(val - bf2f(h));
    if (t == 0) bias[c] = b[cc];
}

// epilogue: tile t, acc -> q (f32) | kvp (interleaved bf16) | skip (f32)
__device__ __forceinline__ void store_tile(
    int t, int quad, int node, floatx4 acc, const float* __restrict__ bias,
    float* __restrict__ q, unsigned short* __restrict__ kvp,
    float* __restrict__ skip)
{
    int cg = t * 16 + quad * 4;
    float r0 = acc[0] + bias[cg + 0];
    float r1 = acc[1] + bias[cg + 1];
    float r2 = acc[2] + bias[cg + 2];
    float r3 = acc[3] + bias[cg + 3];
    if (cg < 128) {
        *(floatx4*)(q + (long)node * 128 + cg) = (floatx4){r0, r1, r2, r3};
    } else if (cg < 384) {
        bool isV = cg >= 256;
        int d0 = cg - (isV ? 256 : 128);          // even, 0..124
        unsigned int p0 = (unsigned int)f2bf(r0) | ((unsigned int)f2bf(r1) << 16);
        unsigned int p1 = (unsigned int)f2bf(r2) | ((unsigned int)f2bf(r3) << 16);
        // lane j layout: [k_{2j}, k_{2j+1}, v_{2j}, v_{2j+1}]
        unsigned int* base = (unsigned int*)(kvp + (long)node * 256 + (d0 >> 1) * 4 + (isV ? 2 : 0));
        base[0] = p0;
        base[2] = p1;
    } else {
        *(floatx4*)(skip + (long)node * 32 + (cg - 384)) = (floatx4){r0, r1, r2, r3};
    }
}

// ---------------- K1: MFMA projection, A-stationary ----------------
// grid = (ceil(N/256), 4). Block = 4 waves. slot = blockIdx.y*4 + wave owns
// tiles {2*slot, 2*slot+1} of 26 (416 cols = q|k|v|skip); A-frags (split-bf16
// hi/lo) loaded ONCE into registers, reused for all 256 nodes of the block
// (8 chunks x 32 nodes staged through LDS as bf16 hi/lo).
template <int L>
__global__ __launch_bounds__(256) void proj_mfma(
    const float* __restrict__ xin,
    const unsigned short* __restrict__ wt_hi,
    const unsigned short* __restrict__ wt_lo,
    const float* __restrict__ bias,
    float* __restrict__ q, unsigned short* __restrict__ kvp,
    float* __restrict__ skip, int N)
{
    constexpr int LP = L + 8;   // ushort pad
    constexpr int KS = L / 32;
    __shared__ unsigned short xh[32 * LP];
    __shared__ unsigned short xl[32 * LP];
    const int tid = threadIdx.x, lane = tid & 63, w = tid >> 6;
    const int li = lane & 15, quad = lane >> 4;
    const int slot = blockIdx.y * 4 + w;      // 0..15; slots 13..15 idle
    const int t0 = slot * 2;
    const bool hasT = t0 < 26;

    // A-frags for this wave's 2 tiles — loaded once, register-resident.
    short8 Ah[2][KS], Al[2][KS];
    if (hasT) {
#pragma unroll
        for (int ti = 0; ti < 2; ti++)
#pragma unroll
            for (int ks = 0; ks < KS; ks++) {
                long off = (long)((t0 + ti) * 16 + li) * L + ks * 32 + quad * 8;
                Ah[ti][ks] = *(const short8*)(wt_hi + off);
                Al[ti][ks] = *(const short8*)(wt_lo + off);
            }
    }

    const int nb0 = blockIdx.x * 256;
    for (int c = 0; c < 8; c++) {
        const int n0 = nb0 + c * 32;
        // stage 32 nodes of X as bf16 hi/lo
        for (int f = tid; f < 32 * (L / 4); f += 256) {
            int row = f / (L / 4);
            int k4 = (f - row * (L / 4)) * 4;
            int n = n0 + row;
            float4 xv = (n < N) ? *(const float4*)(xin + (long)n * L + k4)
                                : make_float4(0.f, 0.f, 0.f, 0.f);
            unsigned short h0 = f2bf(xv.x), h1 = f2bf(xv.y),
                           h2 = f2bf(xv.z), h3 = f2bf(xv.w);
            ushort4v hs = {h0, h1, h2, h3};
            ushort4v ls = {f2bf(xv.x - bf2f(h0)), f2bf(xv.y - bf2f(h1)),
                           f2bf(xv.z - bf2f(h2)), f2bf(xv.w - bf2f(h3))};
            *(ushort4v*)(xh + row * LP + k4) = hs;
            *(ushort4v*)(xl + row * LP + k4) = ls;
        }
        __syncthreads();

        if (hasT) {
#pragma unroll
            for (int half = 0; half < 2; half++) {
                const int node = n0 + half * 16 + li;
                short8 Bh[KS], Bl[KS];
#pragma unroll
                for (int ks = 0; ks < KS; ks++) {
                    int off = (half * 16 + li) * LP + ks * 32 + quad * 8;
                    Bh[ks] = *(const short8*)(xh + off);
                    Bl[ks] = *(const short8*)(xl + off);
                }
#pragma unroll
                for (int ti = 0; ti < 2; ti++) {
                    floatx4 acc = {0.f, 0.f, 0.f, 0.f};
#pragma unroll
                    for (int ks = 0; ks < KS; ks++) {
                        acc = __builtin_amdgcn_mfma_f32_16x16x32_bf16(Ah[ti][ks], Bh[ks], acc, 0, 0, 0);
                        acc = __builtin_amdgcn_mfma_f32_16x16x32_bf16(Ah[ti][ks], Bl[ks], acc, 0, 0, 0);
                        acc = __builtin_amdgcn_mfma_f32_16x16x32_bf16(Al[ti][ks], Bh[ks], acc, 0, 0, 0);
                    }
                    if (node < N)
                        store_tile(t0 + ti, quad, node, acc, bias, q, kvp, skip);
                }
            }
        }
        __syncthreads();
    }
}

// ---------------- K2: fused per-node online-softmax attention + epilogue ----
// one wave per dst node; lane l owns dims {2l, 2l+1}; head = l>>4.
// kvp interleaved bf16 per lane: [k_{2l},k_{2l+1},v_{2l},v_{2l+1}] (8 B).
__global__ __launch_bounds__(256) void attn_kernel(
    const float* __restrict__ q, const unsigned short* __restrict__ kvp,
    const int* __restrict__ rowptr, const int* __restrict__ perm,
    const float* __restrict__ skip, float* __restrict__ h, int N)
{
    const int wid = (blockIdx.x * 256 + threadIdx.x) >> 6;
    const int lane = threadIdx.x & 63;
    if (wid >= N) return;
    const int d = __builtin_amdgcn_readfirstlane(wid);  // uniform -> scalar loads
    const float2 q2 = *(const float2*)(q + (long)d * 128 + lane * 2);
    float m = -INFINITY, den = 0.f;
    float ox = 0.f, oy = 0.f;
    const int beg = rowptr[d], end = rowptr[d + 1];
    const float scale = 0.17677669529663687f;  // 1/sqrt(32)
    int idx = beg;
    for (; idx + 3 < end; idx += 4) {
        int s0 = perm[idx], s1 = perm[idx + 1], s2 = perm[idx + 2], s3 = perm[idx + 3];
        uint2 a0 = *(const uint2*)(kvp + (long)s0 * 256 + lane * 4);
        uint2 a1 = *(const uint2*)(kvp + (long)s1 * 256 + lane * 4);
        uint2 a2 = *(const uint2*)(kvp + (long)s2 * 256 + lane * 4);
        uint2 a3 = *(const uint2*)(kvp + (long)s3 * 256 + lane * 4);
        float p0 = q2.x * __uint_as_float(a0.x << 16) + q2.y * __uint_as_float(a0.x & 0xFFFF0000u);
        float p1 = q2.x * __uint_as_float(a1.x << 16) + q2.y * __uint_as_float(a1.x & 0xFFFF0000u);
        float p2 = q2.x * __uint_as_float(a2.x << 16) + q2.y * __uint_as_float(a2.x & 0xFFFF0000u);
        float p3 = q2.x * __uint_as_float(a3.x << 16) + q2.y * __uint_as_float(a3.x & 0xFFFF0000u);
        p0 += __shfl_xor(p0, 1);  p1 += __shfl_xor(p1, 1);  p2 += __shfl_xor(p2, 1);  p3 += __shfl_xor(p3, 1);
        p0 += __shfl_xor(p0, 2);  p1 += __shfl_xor(p1, 2);  p2 += __shfl_xor(p2, 2);  p3 += __shfl_xor(p3, 2);
        p0 += __shfl_xor(p0, 4);  p1 += __shfl_xor(p1, 4);  p2 += __shfl_xor(p2, 4);  p3 += __shfl_xor(p3, 4);
        p0 += __shfl_xor(p0, 8);  p1 += __shfl_xor(p1, 8);  p2 += __shfl_xor(p2, 8);  p3 += __shfl_xor(p3, 8);
        float l0 = p0 * scale, l1 = p1 * scale, l2 = p2 * scale, l3 = p3 * scale;
        float mb = fmaxf(fmaxf(l0, l1), fmaxf(l2, l3));
        float nm = fmaxf(m, mb);
        float sc = __expf(m - nm);
        float w0 = __expf(l0 - nm), w1 = __expf(l1 - nm),
              w2 = __expf(l2 - nm), w3 = __expf(l3 - nm);
        den = den * sc + ((w0 + w1) + (w2 + w3));
        float vx = w0 * __uint_as_float(a0.y << 16) + w1 * __uint_as_float(a1.y << 16)
                 + w2 * __uint_as_float(a2.y << 16) + w3 * __uint_as_float(a3.y << 16);
        float vy = w0 * __uint_as_float(a0.y & 0xFFFF0000u) + w1 * __uint_as_float(a1.y & 0xFFFF0000u)
                 + w2 * __uint_as_float(a2.y & 0xFFFF0000u) + w3 * __uint_as_float(a3.y & 0xFFFF0000u);
        ox = ox * sc + vx;
        oy = oy * sc + vy;
        m = nm;
    }
    for (; idx < end; idx++) {
        int s0 = perm[idx];
        uint2 a0 = *(const uint2*)(kvp + (long)s0 * 256 + lane * 4);
        float p0 = q2.x * __uint_as_float(a0.x << 16) + q2.y * __uint_as_float(a0.x & 0xFFFF0000u);
        p0 += __shfl_xor(p0, 1);
        p0 += __shfl_xor(p0, 2);
        p0 += __shfl_xor(p0, 4);
        p0 += __shfl_xor(p0, 8);
        float l0 = p0 * scale;
        float nm = fmaxf(m, l0);
        float sc = __expf(m - nm);
        float wt = __expf(l0 - nm);
        den = den * sc + wt;
        ox = ox * sc + wt * __uint_as_float(a0.y << 16);
        oy = oy * sc + wt * __uint_as_float(a0.y & 0xFFFF0000u);
        m = nm;
    }
    float inv = 1.f / (den + 1e-16f);
    ox *= inv; oy *= inv;
    ox += __shfl_xor(ox, 16); oy += __shfl_xor(oy, 16);
    ox += __shfl_xor(ox, 32); oy += __shfl_xor(oy, 32);
    if (lane < 16) {
        float2 sk = *(const float2*)(skip + (long)d * 32 + lane * 2);
        float rx = 0.25f * ox + sk.x;
        float ry = 0.25f * oy + sk.y;
        float2 r = make_float2(rx > 0.f ? rx : 0.f, ry > 0.f ? ry : 0.f);
        *(float2*)(h + (long)d * 32 + lane * 2) = r;
    }
}

// ---------------- K3: final classifier [N,32] @ [32,40] + bc ----------------
__global__ __launch_bounds__(256) void classify_kernel(
    const float* __restrict__ h, const float* __restrict__ wc,
    const float* __restrict__ bc, float* __restrict__ out, int N)
{
    int gid = blockIdx.x * blockDim.x + threadIdx.x;
    if (gid >= N * 40) return;
    int n = gid / 40, o = gid - (gid / 40) * 40;
    float acc = bc[o];
    const float* hr = h + (long)n * 32;
#pragma unroll
    for (int l = 0; l < 32; ++l) acc += hr[l] * wc[l * 40 + o];
    out[gid] = acc;
}

extern "C" void kernel_launch(void* const* d_in, const int* in_sizes, int n_in,
                              void* d_out, int out_size, void* d_ws, size_t ws_size,
                              hipStream_t stream)
{
    const float* x   = (const float*)d_in[0];
    const int* ei    = (const int*)d_in[1];
    const float* wq1 = (const float*)d_in[2];  const float* bq1 = (const float*)d_in[3];
    const float* wk1 = (const float*)d_in[4];  const float* bk1 = (const float*)d_in[5];
    const float* wv1 = (const float*)d_in[6];  const float* bv1 = (const float*)d_in[7];
    const float* ws1 = (const float*)d_in[8];  const float* bs1 = (const float*)d_in[9];
    const float* wq2 = (const float*)d_in[10]; const float* bq2 = (const float*)d_in[11];
    const float* wk2 = (const float*)d_in[12]; const float* bk2 = (const float*)d_in[13];
    const float* wv2 = (const float*)d_in[14]; const float* bv2 = (const float*)d_in[15];
    const float* ws2 = (const float*)d_in[16]; const float* bs2 = (const float*)d_in[17];
    const float* wc  = (const float*)d_in[18]; const float* bc  = (const float*)d_in[19];

    const int N = in_sizes[0] / 128;   // 50000
    const int E = in_sizes[1] / 2;     // 800000
    const int* src = ei;
    const int* dst = ei + E;

    // workspace layout (bytes, 256-aligned chunks)
    char* p = (char*)d_ws;
    auto take = [&](size_t bytes) { char* r = p; p += (bytes + 255) & ~(size_t)255; return r; };
    float* q             = (float*)take((size_t)N * 128 * 4);
    unsigned short* kvp  = (unsigned short*)take((size_t)N * 256 * 2);
    float* skip          = (float*)take((size_t)N * 32 * 4);
    float* h1            = (float*)take((size_t)N * 32 * 4);
    float* h2            = (float*)take((size_t)N * 32 * 4);
    unsigned short* wt1h = (unsigned short*)take(416 * 128 * 2);
    unsigned short* wt1l = (unsigned short*)take(416 * 128 * 2);
    unsigned short* wt2h = (unsigned short*)take(416 * 32 * 2);
    unsigned short* wt2l = (unsigned short*)take(416 * 32 * 2);
    float* bias1         = (float*)take(416 * 4);
    float* bias2         = (float*)take(416 * 4);
    int* deg             = (int*)take((size_t)N * 4);
    int* rowptr          = (int*)take((size_t)(N + 1) * 4);
    int* cursor          = (int*)take((size_t)N * 4);
    int* perm            = (int*)take((size_t)E * 4);

    const dim3 projGrid((N + 255) / 256, 4);
    const int eGrid    = (E + 255) / 256;
    const int attnGrid = (N + 3) / 4;          // 4 waves/block

    // ---------------- weight prep + CSR build ----------------
    wprep_kernel<128><<<416, 128, 0, stream>>>(wq1, bq1, wk1, bk1, wv1, bv1,
                                               ws1, bs1, wt1h, wt1l, bias1);
    wprep_kernel<32><<<416, 32, 0, stream>>>(wq2, bq2, wk2, bk2, wv2, bv2,
                                             ws2, bs2, wt2h, wt2l, bias2);
    hipMemsetAsync(deg, 0, (size_t)N * 4, stream);
    hist_kernel<<<eGrid, 256, 0, stream>>>(dst, deg, E);
    scan_kernel<<<1, 1024, 0, stream>>>(deg, rowptr, cursor, N);
    fill_kernel<<<eGrid, 256, 0, stream>>>(src, dst, cursor, perm, E);

    // ---------------- layer 1 ----------------
    proj_mfma<128><<<projGrid, 256, 0, stream>>>(x, wt1h, wt1l, bias1, q, kvp, skip, N);
    attn_kernel<<<attnGrid, 256, 0, stream>>>(q, kvp, rowptr, perm, skip, h1, N);

    // ---------------- layer 2 ----------------
    proj_mfma<32><<<projGrid, 256, 0, stream>>>(h1, wt2h, wt2l, bias2, q, kvp, skip, N);
    attn_kernel<<<attnGrid, 256, 0, stream>>>(q, kvp, rowptr, perm, skip, h2, N);

    // ---------------- classifier ----------------
    classify_kernel<<<(N * 40 + 255) / 256, 256, 0, stream>>>(h2, wc, bc, (float*)d_out, N);
}

// Round 9
// 380.260 us; speedup vs baseline: 1.8599x; 1.2062x over previous
//
#include <hip/hip_runtime.h>
#include <hip/hip_bf16.h>

typedef __attribute__((ext_vector_type(8))) short short8;       // 8 bf16 (A/B frag)
typedef __attribute__((ext_vector_type(4))) float floatx4;      // C/D frag
typedef __attribute__((ext_vector_type(4))) unsigned short ushort4v;

__device__ inline unsigned short f2bf(float x) {                 // RNE f32->bf16 bits
    unsigned int u = __float_as_uint(x);
    u += 0x7FFFu + ((u >> 16) & 1u);
    return (unsigned short)(u >> 16);
}
__device__ inline float bf2f(unsigned short h) {
    return __uint_as_float(((unsigned int)h) << 16);
}

// ---------------- CSR build ----------------
__global__ __launch_bounds__(256) void hist_kernel(
    const int* __restrict__ dst, int* __restrict__ deg, int E)
{
    int e = blockIdx.x * blockDim.x + threadIdx.x;
    if (e < E) atomicAdd(&deg[dst[e]], 1);
}

// hierarchical scan: block sums -> top scan (<=64 blocks) -> add-back
__global__ __launch_bounds__(256) void scan_part(
    const int* __restrict__ deg, int* __restrict__ bsum, int N)
{
    __shared__ int ws[4];
    const int base = blockIdx.x * 1024;
    const int tid = threadIdx.x, lane = tid & 63, w = tid >> 6;
    int s = 0;
#pragma unroll
    for (int j = 0; j < 4; j++) {
        int i = base + j * 256 + tid;
        if (i < N) s += deg[i];
    }
#pragma unroll
    for (int off = 1; off < 64; off <<= 1) s += __shfl_xor(s, off, 64);
    if (lane == 0) ws[w] = s;
    __syncthreads();
    if (tid == 0) bsum[blockIdx.x] = ws[0] + ws[1] + ws[2] + ws[3];
}

__global__ __launch_bounds__(64) void scan_tops(
    const int* __restrict__ bsum, int* __restrict__ boff,
    int* __restrict__ rowptr, int nb, int N)
{
    int lane = threadIdx.x;
    int v = (lane < nb) ? bsum[lane] : 0;
    int inc = v;
#pragma unroll
    for (int off = 1; off < 64; off <<= 1) {
        int t = __shfl_up(inc, off, 64);
        if (lane >= off) inc += t;
    }
    if (lane < nb) boff[lane] = inc - v;
    if (lane == 63) rowptr[N] = inc;
}

__global__ __launch_bounds__(256) void scan_final(
    const int* __restrict__ deg, const int* __restrict__ boff,
    int* __restrict__ rowptr, int* __restrict__ cursor, int N)
{
    __shared__ int woff[4];
    const int base = blockIdx.x * 1024;
    const int tid = threadIdx.x, lane = tid & 63, w = tid >> 6;
    const int i0 = base + tid * 4;
    int v0 = (i0     < N) ? deg[i0]     : 0;
    int v1 = (i0 + 1 < N) ? deg[i0 + 1] : 0;
    int v2 = (i0 + 2 < N) ? deg[i0 + 2] : 0;
    int v3 = (i0 + 3 < N) ? deg[i0 + 3] : 0;
    int ts = v0 + v1 + v2 + v3;
    int inc = ts;
#pragma unroll
    for (int off = 1; off < 64; off <<= 1) {
        int t = __shfl_up(inc, off, 64);
        if (lane >= off) inc += t;
    }
    if (lane == 63) woff[w] = inc;
    __syncthreads();
    int wpre = 0;
    if (w > 0) wpre += woff[0];
    if (w > 1) wpre += woff[1];
    if (w > 2) wpre += woff[2];
    int exc = boff[blockIdx.x] + wpre + inc - ts;
    int p0 = exc, p1 = exc + v0, p2 = p1 + v1, p3 = p2 + v2;
    if (i0     < N) { rowptr[i0]     = p0; cursor[i0]     = p0; }
    if (i0 + 1 < N) { rowptr[i0 + 1] = p1; cursor[i0 + 1] = p1; }
    if (i0 + 2 < N) { rowptr[i0 + 2] = p2; cursor[i0 + 2] = p2; }
    if (i0 + 3 < N) { rowptr[i0 + 3] = p3; cursor[i0 + 3] = p3; }
}

__global__ __launch_bounds__(256) void fill_kernel(
    const int* __restrict__ src, const int* __restrict__ dst,
    int* __restrict__ cursor, int* __restrict__ perm, int E)
{
    int e = blockIdx.x * blockDim.x + threadIdx.x;
    if (e >= E) return;
    int pos = atomicAdd(&cursor[dst[e]], 1);
    perm[pos] = src[e];
}

// ---------------- weight prep: Wt[col][k] hi/lo bf16 + bias concat ----------
// col 0..127 = wq, 128..255 = wk, 256..383 = wv, 384..415 = ws
template <int L>
__global__ void wprep_kernel(
    const float* __restrict__ wq, const float* __restrict__ bq,
    const float* __restrict__ wk, const float* __restrict__ bk,
    const float* __restrict__ wv, const float* __restrict__ bv,
    const float* __restrict__ ws, const float* __restrict__ bs,
    unsigned short* __restrict__ wt_hi, unsigned short* __restrict__ wt_lo,
    float* __restrict__ bias)
{
    int c = blockIdx.x;   // 0..415
    int t = threadIdx.x;  // 0..L-1
    const float* w; const float* b; int cc, ncols;
    if (c < 384) {
        int m = c >> 7; cc = c & 127; ncols = 128;
        w = (m == 0) ? wq : ((m == 1) ? wk : wv);
        b = (m == 0) ? bq : ((m == 1) ? bk : bv);
    } else {
        cc = c - 384; ncols = 32; w = ws; b = bs;
    }
    float val = w[t * ncols + cc];
    unsigned short h = f2bf(val);
    wt_hi[c * L + t] = h;
    wt_lo[c * L + t] = f2bf(val - bf2f(h));
    if (t == 0) bias[c] = b[cc];
}

// ---------------- K1: MFMA projection, A-stationary, coalesced stores -------
// grid = (ceil(N/256), 4). Block = 4 waves. slot = blockIdx.y*4+w (0..15).
// Tile pairs (of 26 16-col tiles: q=0..7, k=8..15, v=16..23, skip=24..25):
//   slot 0..3  -> (2s, 2s+1)     : 32 adjacent q cols
//   slot 4..11 -> (8+i, 16+i)    : k-tile i + matching v-tile i (i=slot-4)
//   slot 12    -> (24, 25)       : skip
//   slot 13..15 idle (stage+barriers only).
// A-frags register-resident; X staged per 32-node chunk, double-buffered.
// Epilogue: per-wave LDS transpose -> full-line coalesced global stores.
template <int L>
__global__ __launch_bounds__(256) void proj_mfma(
    const float* __restrict__ xin,
    const unsigned short* __restrict__ wt_hi,
    const unsigned short* __restrict__ wt_lo,
    const float* __restrict__ bias,
    float* __restrict__ q, unsigned short* __restrict__ kvp,
    float* __restrict__ skip, int N)
{
    constexpr int LP = L + 8;          // ushort pad
    constexpr int KS = L / 32;
    constexpr int SI = (32 * (L / 4)) / 256;  // staging float4s/thread (128->4, 32->1)
    __shared__ unsigned short xh[2][32 * LP];
    __shared__ unsigned short xl[2][32 * LP];
    __shared__ float scr[4][32 * 36];  // per-wave transpose scratch
    const int tid = threadIdx.x, lane = tid & 63, w = tid >> 6;
    const int li = lane & 15, quad = lane >> 4;
    const int slot = __builtin_amdgcn_readfirstlane(blockIdx.y * 4 + w);
    const bool hasT = slot < 13;

    int t0 = 24, t1 = 25;
    if (slot < 4)       { t0 = slot * 2; t1 = t0 + 1; }
    else if (slot < 12) { t0 = 4 + slot; t1 = 12 + slot; }   // k=8+i, v=16+i

    // A-frags + bias loaded once
    short8 Ah[2][KS], Al[2][KS];
    float bias_r[2][4];
    if (hasT) {
#pragma unroll
        for (int ti = 0; ti < 2; ti++) {
            int tt = ti ? t1 : t0;
#pragma unroll
            for (int ks = 0; ks < KS; ks++) {
                long off = (long)(tt * 16 + li) * L + ks * 32 + quad * 8;
                Ah[ti][ks] = *(const short8*)(wt_hi + off);
                Al[ti][ks] = *(const short8*)(wt_lo + off);
            }
#pragma unroll
            for (int r = 0; r < 4; r++)
                bias_r[ti][r] = bias[tt * 16 + quad * 4 + r];
        }
    }

    const int nb0 = blockIdx.x * 256;
    float* myscr = scr[w];
    unsigned int* su = (unsigned int*)myscr;

    float4 xv[SI];
    auto issue_loads = [&](int c) {
#pragma unroll
        for (int s = 0; s < SI; s++) {
            int f = s * 256 + tid;
            int row = f / (L / 4), c4 = (f - row * (L / 4)) * 4;
            int n = nb0 + c * 32 + row;
            xv[s] = (n < N) ? *(const float4*)(xin + (long)n * L + c4)
                            : make_float4(0.f, 0.f, 0.f, 0.f);
        }
    };
    auto cvt_store = [&](int buf) {
#pragma unroll
        for (int s = 0; s < SI; s++) {
            int f = s * 256 + tid;
            int row = f / (L / 4), c4 = (f - row * (L / 4)) * 4;
            unsigned short h0 = f2bf(xv[s].x), h1 = f2bf(xv[s].y),
                           h2 = f2bf(xv[s].z), h3 = f2bf(xv[s].w);
            ushort4v hs = {h0, h1, h2, h3};
            ushort4v ls = {f2bf(xv[s].x - bf2f(h0)), f2bf(xv[s].y - bf2f(h1)),
                           f2bf(xv[s].z - bf2f(h2)), f2bf(xv[s].w - bf2f(h3))};
            *(ushort4v*)(xh[buf] + row * LP + c4) = hs;
            *(ushort4v*)(xl[buf] + row * LP + c4) = ls;
        }
    };

    issue_loads(0);
    cvt_store(0);
    __syncthreads();

    for (int c = 0; c < 8; c++) {
        if (c < 7) issue_loads(c + 1);
        const int n0c = nb0 + c * 32;
        if (hasT) {
            const int buf = c & 1;
#pragma unroll
            for (int half = 0; half < 2; half++) {
                short8 Bh[KS], Bl[KS];
#pragma unroll
                for (int ks = 0; ks < KS; ks++) {
                    int off = (half * 16 + li) * LP + ks * 32 + quad * 8;
                    Bh[ks] = *(const short8*)(xh[buf] + off);
                    Bl[ks] = *(const short8*)(xl[buf] + off);
                }
                floatx4 accv[2];
#pragma unroll
                for (int ti = 0; ti < 2; ti++) {
                    floatx4 acc = {0.f, 0.f, 0.f, 0.f};
#pragma unroll
                    for (int ks = 0; ks < KS; ks++) {
                        acc = __builtin_amdgcn_mfma_f32_16x16x32_bf16(Ah[ti][ks], Bh[ks], acc, 0, 0, 0);
                        acc = __builtin_amdgcn_mfma_f32_16x16x32_bf16(Ah[ti][ks], Bl[ks], acc, 0, 0, 0);
                        acc = __builtin_amdgcn_mfma_f32_16x16x32_bf16(Al[ti][ks], Bh[ks], acc, 0, 0, 0);
                    }
#pragma unroll
                    for (int r = 0; r < 4; r++) acc[r] += bias_r[ti][r];
                    accv[ti] = acc;
                }
                const int row = half * 16 + li;
                if (slot < 4 || slot == 12) {
                    // f32 paths: scratch [32][36] floats, cols ti*16+quad*4
                    *(floatx4*)(myscr + row * 36 + quad * 4)      = accv[0];
                    *(floatx4*)(myscr + row * 36 + 16 + quad * 4) = accv[1];
                } else {
                    // k/v pair: pack [k01,v01,k23,v23] at uint su[row*20 + quad*4]
                    unsigned int k01 = (unsigned int)f2bf(accv[0][0]) | ((unsigned int)f2bf(accv[0][1]) << 16);
                    unsigned int k23 = (unsigned int)f2bf(accv[0][2]) | ((unsigned int)f2bf(accv[0][3]) << 16);
                    unsigned int v01 = (unsigned int)f2bf(accv[1][0]) | ((unsigned int)f2bf(accv[1][1]) << 16);
                    unsigned int v23 = (unsigned int)f2bf(accv[1][2]) | ((unsigned int)f2bf(accv[1][3]) << 16);
                    uint4 pk = make_uint4(k01, v01, k23, v23);
                    *(uint4*)(su + row * 20 + quad * 4) = pk;
                }
            }
            // coalesced read-out (per-wave scratch; wave-internal LDS dep)
            if (slot < 4) {
#pragma unroll
                for (int it = 0; it < 4; it++) {
                    int idx = it * 64 + lane;
                    int nl = idx >> 3, seg = idx & 7;
                    int node = n0c + nl;
                    if (node < N) {
                        floatx4 vv = *(floatx4*)(myscr + nl * 36 + seg * 4);
                        *(floatx4*)(q + (long)node * 128 + slot * 32 + seg * 4) = vv;
                    }
                }
            } else if (slot == 12) {
#pragma unroll
                for (int it = 0; it < 4; it++) {
                    int idx = it * 64 + lane;
                    int nl = idx >> 3, seg = idx & 7;
                    int node = n0c + nl;
                    if (node < N) {
                        floatx4 vv = *(floatx4*)(myscr + nl * 36 + seg * 4);
                        *(floatx4*)(skip + (long)node * 32 + seg * 4) = vv;
                    }
                }
            } else {
                const int i = slot - 4;
#pragma unroll
                for (int it = 0; it < 2; it++) {
                    int idx = it * 64 + lane;
                    int nl = idx >> 2, part = idx & 3;
                    int node = n0c + nl;
                    if (node < N) {
                        uint4 vv = *(uint4*)(su + nl * 20 + part * 4);
                        *(uint4*)((unsigned int*)(kvp + (long)node * 256) + i * 16 + part * 4) = vv;
                    }
                }
            }
        }
        __syncthreads();
        if (c < 7) cvt_store((c + 1) & 1);
        __syncthreads();
    }
}

// ---------------- K2: fused per-node online-softmax attention + epilogue ----
// one wave per dst node; lane l owns dims {2l, 2l+1}; head = l>>4.
// kvp interleaved bf16 per lane: [k_{2l},k_{2l+1},v_{2l},v_{2l+1}] (8 B).
__global__ __launch_bounds__(256) void attn_kernel(
    const float* __restrict__ q, const unsigned short* __restrict__ kvp,
    const int* __restrict__ rowptr, const int* __restrict__ perm,
    const float* __restrict__ skip, float* __restrict__ h, int N)
{
    const int wid = (blockIdx.x * 256 + threadIdx.x) >> 6;
    const int lane = threadIdx.x & 63;
    if (wid >= N) return;
    const int d = __builtin_amdgcn_readfirstlane(wid);
    const float2 q2 = *(const float2*)(q + (long)d * 128 + lane * 2);
    float m = -INFINITY, den = 0.f;
    float ox = 0.f, oy = 0.f;
    const int beg = rowptr[d], end = rowptr[d + 1];
    const float scale = 0.17677669529663687f;  // 1/sqrt(32)
    int idx = beg;
    for (; idx + 3 < end; idx += 4) {
        int s0 = perm[idx], s1 = perm[idx + 1], s2 = perm[idx + 2], s3 = perm[idx + 3];
        uint2 a0 = *(const uint2*)(kvp + (long)s0 * 256 + lane * 4);
        uint2 a1 = *(const uint2*)(kvp + (long)s1 * 256 + lane * 4);
        uint2 a2 = *(const uint2*)(kvp + (long)s2 * 256 + lane * 4);
        uint2 a3 = *(const uint2*)(kvp + (long)s3 * 256 + lane * 4);
        float p0 = q2.x * __uint_as_float(a0.x << 16) + q2.y * __uint_as_float(a0.x & 0xFFFF0000u);
        float p1 = q2.x * __uint_as_float(a1.x << 16) + q2.y * __uint_as_float(a1.x & 0xFFFF0000u);
        float p2 = q2.x * __uint_as_float(a2.x << 16) + q2.y * __uint_as_float(a2.x & 0xFFFF0000u);
        float p3 = q2.x * __uint_as_float(a3.x << 16) + q2.y * __uint_as_float(a3.x & 0xFFFF0000u);
        p0 += __shfl_xor(p0, 1);  p1 += __shfl_xor(p1, 1);  p2 += __shfl_xor(p2, 1);  p3 += __shfl_xor(p3, 1);
        p0 += __shfl_xor(p0, 2);  p1 += __shfl_xor(p1, 2);  p2 += __shfl_xor(p2, 2);  p3 += __shfl_xor(p3, 2);
        p0 += __shfl_xor(p0, 4);  p1 += __shfl_xor(p1, 4);  p2 += __shfl_xor(p2, 4);  p3 += __shfl_xor(p3, 4);
        p0 += __shfl_xor(p0, 8);  p1 += __shfl_xor(p1, 8);  p2 += __shfl_xor(p2, 8);  p3 += __shfl_xor(p3, 8);
        float l0 = p0 * scale, l1 = p1 * scale, l2 = p2 * scale, l3 = p3 * scale;
        float mb = fmaxf(fmaxf(l0, l1), fmaxf(l2, l3));
        float nm = fmaxf(m, mb);
        float sc = __expf(m - nm);
        float w0 = __expf(l0 - nm), w1 = __expf(l1 - nm),
              w2 = __expf(l2 - nm), w3 = __expf(l3 - nm);
        den = den * sc + ((w0 + w1) + (w2 + w3));
        float vx = w0 * __uint_as_float(a0.y << 16) + w1 * __uint_as_float(a1.y << 16)
                 + w2 * __uint_as_float(a2.y << 16) + w3 * __uint_as_float(a3.y << 16);
        float vy = w0 * __uint_as_float(a0.y & 0xFFFF0000u) + w1 * __uint_as_float(a1.y & 0xFFFF0000u)
                 + w2 * __uint_as_float(a2.y & 0xFFFF0000u) + w3 * __uint_as_float(a3.y & 0xFFFF0000u);
        ox = ox * sc + vx;
        oy = oy * sc + vy;
        m = nm;
    }
    for (; idx < end; idx++) {
        int s0 = perm[idx];
        uint2 a0 = *(const uint2*)(kvp + (long)s0 * 256 + lane * 4);
        float p0 = q2.x * __uint_as_float(a0.x << 16) + q2.y * __uint_as_float(a0.x & 0xFFFF0000u);
        p0 += __shfl_xor(p0, 1);
        p0 += __shfl_xor(p0, 2);
        p0 += __shfl_xor(p0, 4);
        p0 += __shfl_xor(p0, 8);
        float l0 = p0 * scale;
        float nm = fmaxf(m, l0);
        float sc = __expf(m - nm);
        float wt = __expf(l0 - nm);
        den = den * sc + wt;
        ox = ox * sc + wt * __uint_as_float(a0.y << 16);
        oy = oy * sc + wt * __uint_as_float(a0.y & 0xFFFF0000u);
        m = nm;
    }
    float inv = 1.f / (den + 1e-16f);
    ox *= inv; oy *= inv;
    ox += __shfl_xor(ox, 16); oy += __shfl_xor(oy, 16);
    ox += __shfl_xor(ox, 32); oy += __shfl_xor(oy, 32);
    if (lane < 16) {
        float2 sk = *(const float2*)(skip + (long)d * 32 + lane * 2);
        float rx = 0.25f * ox + sk.x;
        float ry = 0.25f * oy + sk.y;
        float2 r = make_float2(rx > 0.f ? rx : 0.f, ry > 0.f ? ry : 0.f);
        *(float2*)(h + (long)d * 32 + lane * 2) = r;
    }
}

// ---------------- K3: final classifier [N,32] @ [32,40] + bc ----------------
__global__ __launch_bounds__(256) void classify_kernel(
    const float* __restrict__ h, const float* __restrict__ wc,
    const float* __restrict__ bc, float* __restrict__ out, int N)
{
    int gid = blockIdx.x * blockDim.x + threadIdx.x;
    if (gid >= N * 40) return;
    int n = gid / 40, o = gid - (gid / 40) * 40;
    float acc = bc[o];
    const float* hr = h + (long)n * 32;
#pragma unroll
    for (int l = 0; l < 32; ++l) acc += hr[l] * wc[l * 40 + o];
    out[gid] = acc;
}

extern "C" void kernel_launch(void* const* d_in, const int* in_sizes, int n_in,
                              void* d_out, int out_size, void* d_ws, size_t ws_size,
                              hipStream_t stream)
{
    const float* x   = (const float*)d_in[0];
    const int* ei    = (const int*)d_in[1];
    const float* wq1 = (const float*)d_in[2];  const float* bq1 = (const float*)d_in[3];
    const float* wk1 = (const float*)d_in[4];  const float* bk1 = (const float*)d_in[5];
    const float* wv1 = (const float*)d_in[6];  const float* bv1 = (const float*)d_in[7];
    const float* ws1 = (const float*)d_in[8];  const float* bs1 = (const float*)d_in[9];
    const float* wq2 = (const float*)d_in[10]; const float* bq2 = (const float*)d_in[11];
    const float* wk2 = (const float*)d_in[12]; const float* bk2 = (const float*)d_in[13];
    const float* wv2 = (const float*)d_in[14]; const float* bv2 = (const float*)d_in[15];
    const float* ws2 = (const float*)d_in[16]; const float* bs2 = (const float*)d_in[17];
    const float* wc  = (const float*)d_in[18]; const float* bc  = (const float*)d_in[19];

    const int N = in_sizes[0] / 128;   // 50000
    const int E = in_sizes[1] / 2;     // 800000
    const int* src = ei;
    const int* dst = ei + E;

    // workspace layout (bytes, 256-aligned chunks)
    char* p = (char*)d_ws;
    auto take = [&](size_t bytes) { char* r = p; p += (bytes + 255) & ~(size_t)255; return r; };
    float* q             = (float*)take((size_t)N * 128 * 4);
    unsigned short* kvp  = (unsigned short*)take((size_t)N * 256 * 2);
    float* skip          = (float*)take((size_t)N * 32 * 4);
    float* h1            = (float*)take((size_t)N * 32 * 4);
    float* h2            = (float*)take((size_t)N * 32 * 4);
    unsigned short* wt1h = (unsigned short*)take(416 * 128 * 2);
    unsigned short* wt1l = (unsigned short*)take(416 * 128 * 2);
    unsigned short* wt2h = (unsigned short*)take(416 * 32 * 2);
    unsigned short* wt2l = (unsigned short*)take(416 * 32 * 2);
    float* bias1         = (float*)take(416 * 4);
    float* bias2         = (float*)take(416 * 4);
    int* deg             = (int*)take((size_t)N * 4);
    int* rowptr          = (int*)take((size_t)(N + 1) * 4);
    int* cursor          = (int*)take((size_t)N * 4);
    int* perm            = (int*)take((size_t)E * 4);
    int* bsum            = (int*)take(64 * 4);
    int* boff            = (int*)take(64 * 4);

    const dim3 projGrid((N + 255) / 256, 4);
    const int eGrid    = (E + 255) / 256;
    const int attnGrid = (N + 3) / 4;          // 4 waves/block
    const int nb       = (N + 1023) / 1024;    // <= 64

    // ---------------- weight prep + CSR build ----------------
    wprep_kernel<128><<<416, 128, 0, stream>>>(wq1, bq1, wk1, bk1, wv1, bv1,
                                               ws1, bs1, wt1h, wt1l, bias1);
    wprep_kernel<32><<<416, 32, 0, stream>>>(wq2, bq2, wk2, bk2, wv2, bv2,
                                             ws2, bs2, wt2h, wt2l, bias2);
    hipMemsetAsync(deg, 0, (size_t)N * 4, stream);
    hist_kernel<<<eGrid, 256, 0, stream>>>(dst, deg, E);
    scan_part<<<nb, 256, 0, stream>>>(deg, bsum, N);
    scan_tops<<<1, 64, 0, stream>>>(bsum, boff, rowptr, nb, N);
    scan_final<<<nb, 256, 0, stream>>>(deg, boff, rowptr, cursor, N);
    fill_kernel<<<eGrid, 256, 0, stream>>>(src, dst, cursor, perm, E);

    // ---------------- layer 1 ----------------
    proj_mfma<128><<<projGrid, 256, 0, stream>>>(x, wt1h, wt1l, bias1, q, kvp, skip, N);
    attn_kernel<<<attnGrid, 256, 0, stream>>>(q, kvp, rowptr, perm, skip, h1, N);

    // ---------------- layer 2 ----------------
    proj_mfma<32><<<projGrid, 256, 0, stream>>>(h1, wt2h, wt2l, bias2, q, kvp, skip, N);
    attn_kernel<<<attnGrid, 256, 0, stream>>>(q, kvp, rowptr, perm, skip, h2, N);

    // ---------------- classifier ----------------
    classify_kernel<<<(N * 40 + 255) / 256, 256, 0, stream>>>(h2, wc, bc, (float*)d_out, N);
}

// Round 11
// 379.470 us; speedup vs baseline: 1.8637x; 1.0021x over previous
//
#include <hip/hip_runtime.h>
#include <hip/hip_bf16.h>

typedef __attribute__((ext_vector_type(8))) short short8;       // 8 bf16 (A/B frag)
typedef __attribute__((ext_vector_type(4))) float floatx4;      // C/D frag
typedef __attribute__((ext_vector_type(4))) unsigned short ushort4v;

__device__ inline unsigned short f2bf(float x) {                 // RNE f32->bf16 bits
    unsigned int u = __float_as_uint(x);
    u += 0x7FFFu + ((u >> 16) & 1u);
    return (unsigned short)(u >> 16);
}
__device__ inline float bf2f(unsigned short h) {
    return __uint_as_float(((unsigned int)h) << 16);
}
__device__ inline float blo(unsigned int u) { return __uint_as_float(u << 16); }
__device__ inline float bhi(unsigned int u) { return __uint_as_float(u & 0xFFFF0000u); }

// ---------------- CSR build ----------------
__global__ __launch_bounds__(256) void hist_kernel(
    const int* __restrict__ dst, int* __restrict__ deg, int E)
{
    int e = blockIdx.x * blockDim.x + threadIdx.x;
    if (e < E) atomicAdd(&deg[dst[e]], 1);
}

// hierarchical scan: block sums -> top scan (<=64 blocks) -> add-back
__global__ __launch_bounds__(256) void scan_part(
    const int* __restrict__ deg, int* __restrict__ bsum, int N)
{
    __shared__ int ws[4];
    const int base = blockIdx.x * 1024;
    const int tid = threadIdx.x, lane = tid & 63, w = tid >> 6;
    int s = 0;
#pragma unroll
    for (int j = 0; j < 4; j++) {
        int i = base + j * 256 + tid;
        if (i < N) s += deg[i];
    }
#pragma unroll
    for (int off = 1; off < 64; off <<= 1) s += __shfl_xor(s, off, 64);
    if (lane == 0) ws[w] = s;
    __syncthreads();
    if (tid == 0) bsum[blockIdx.x] = ws[0] + ws[1] + ws[2] + ws[3];
}

__global__ __launch_bounds__(64) void scan_tops(
    const int* __restrict__ bsum, int* __restrict__ boff,
    int* __restrict__ rowptr, int nb, int N)
{
    int lane = threadIdx.x;
    int v = (lane < nb) ? bsum[lane] : 0;
    int inc = v;
#pragma unroll
    for (int off = 1; off < 64; off <<= 1) {
        int t = __shfl_up(inc, off, 64);
        if (lane >= off) inc += t;
    }
    if (lane < nb) boff[lane] = inc - v;
    if (lane == 63) rowptr[N] = inc;
}

__global__ __launch_bounds__(256) void scan_final(
    const int* __restrict__ deg, const int* __restrict__ boff,
    int* __restrict__ rowptr, int* __restrict__ cursor, int N)
{
    __shared__ int woff[4];
    const int base = blockIdx.x * 1024;
    const int tid = threadIdx.x, lane = tid & 63, w = tid >> 6;
    const int i0 = base + tid * 4;
    int v0 = (i0     < N) ? deg[i0]     : 0;
    int v1 = (i0 + 1 < N) ? deg[i0 + 1] : 0;
    int v2 = (i0 + 2 < N) ? deg[i0 + 2] : 0;
    int v3 = (i0 + 3 < N) ? deg[i0 + 3] : 0;
    int ts = v0 + v1 + v2 + v3;
    int inc = ts;
#pragma unroll
    for (int off = 1; off < 64; off <<= 1) {
        int t = __shfl_up(inc, off, 64);
        if (lane >= off) inc += t;
    }
    if (lane == 63) woff[w] = inc;
    __syncthreads();
    int wpre = 0;
    if (w > 0) wpre += woff[0];
    if (w > 1) wpre += woff[1];
    if (w > 2) wpre += woff[2];
    int exc = boff[blockIdx.x] + wpre + inc - ts;
    int p0 = exc, p1 = exc + v0, p2 = p1 + v1, p3 = p2 + v2;
    if (i0     < N) { rowptr[i0]     = p0; cursor[i0]     = p0; }
    if (i0 + 1 < N) { rowptr[i0 + 1] = p1; cursor[i0 + 1] = p1; }
    if (i0 + 2 < N) { rowptr[i0 + 2] = p2; cursor[i0 + 2] = p2; }
    if (i0 + 3 < N) { rowptr[i0 + 3] = p3; cursor[i0 + 3] = p3; }
}

__global__ __launch_bounds__(256) void fill_kernel(
    const int* __restrict__ src, const int* __restrict__ dst,
    int* __restrict__ cursor, int* __restrict__ perm, int E)
{
    int e = blockIdx.x * blockDim.x + threadIdx.x;
    if (e >= E) return;
    int pos = atomicAdd(&cursor[dst[e]], 1);
    perm[pos] = src[e];
}

// ---------------- weight prep (both layers fused): Wt[col][k] hi/lo bf16 ----
// blockIdx 0..415 -> layer1 (L=128), 416..831 -> layer2 (L=32).
// col map: 0..127 wq, 128..255 wk, 256..383 wv, 384..415 ws.
__global__ __launch_bounds__(128) void wprep_all(
    const float* __restrict__ wq1, const float* __restrict__ bq1,
    const float* __restrict__ wk1, const float* __restrict__ bk1,
    const float* __restrict__ wv1, const float* __restrict__ bv1,
    const float* __restrict__ ws1, const float* __restrict__ bs1,
    const float* __restrict__ wq2, const float* __restrict__ bq2,
    const float* __restrict__ wk2, const float* __restrict__ bk2,
    const float* __restrict__ wv2, const float* __restrict__ bv2,
    const float* __restrict__ ws2, const float* __restrict__ bs2,
    unsigned short* __restrict__ wt1h, unsigned short* __restrict__ wt1l,
    float* __restrict__ bias1,
    unsigned short* __restrict__ wt2h, unsigned short* __restrict__ wt2l,
    float* __restrict__ bias2)
{
    const int layer = (blockIdx.x >= 416) ? 1 : 0;
    const int c = blockIdx.x - layer * 416;
    const int t = threadIdx.x;
    const int L = layer ? 32 : 128;
    if (t >= L) return;
    const float* w; const float* b; int cc, ncols;
    if (c < 384) {
        int m = c >> 7; cc = c & 127; ncols = 128;
        if (layer == 0) {
            w = (m == 0) ? wq1 : ((m == 1) ? wk1 : wv1);
            b = (m == 0) ? bq1 : ((m == 1) ? bk1 : bv1);
        } else {
            w = (m == 0) ? wq2 : ((m == 1) ? wk2 : wv2);
            b = (m == 0) ? bq2 : ((m == 1) ? bk2 : bv2);
        }
    } else {
        cc = c - 384; ncols = 32;
        w = layer ? ws2 : ws1; b = layer ? bs2 : bs1;
    }
    unsigned short* wh = layer ? wt2h : wt1h;
    unsigned short* wl = layer ? wt2l : wt1l;
    float* bias = layer ? bias2 : bias1;
    float val = w[t * ncols + cc];
    unsigned short h = f2bf(val);
    wh[c * L + t] = h;
    wl[c * L + t] = f2bf(val - bf2f(h));
    if (t == 0) bias[c] = b[cc];
}

// ---------------- K1: MFMA projection, A-stationary, coalesced stores -------
// (unchanged from R9 — see comments there)
template <int L>
__global__ __launch_bounds__(256) void proj_mfma(
    const float* __restrict__ xin,
    const unsigned short* __restrict__ wt_hi,
    const unsigned short* __restrict__ wt_lo,
    const float* __restrict__ bias,
    float* __restrict__ q, unsigned short* __restrict__ kvp,
    float* __restrict__ skip, int N)
{
    constexpr int LP = L + 8;          // ushort pad
    constexpr int KS = L / 32;
    constexpr int SI = (32 * (L / 4)) / 256;
    __shared__ unsigned short xh[2][32 * LP];
    __shared__ unsigned short xl[2][32 * LP];
    __shared__ float scr[4][32 * 36];
    const int tid = threadIdx.x, lane = tid & 63, w = tid >> 6;
    const int li = lane & 15, quad = lane >> 4;
    const int slot = __builtin_amdgcn_readfirstlane(blockIdx.y * 4 + w);
    const bool hasT = slot < 13;

    int t0 = 24, t1 = 25;
    if (slot < 4)       { t0 = slot * 2; t1 = t0 + 1; }
    else if (slot < 12) { t0 = 4 + slot; t1 = 12 + slot; }   // k=8+i, v=16+i

    short8 Ah[2][KS], Al[2][KS];
    float bias_r[2][4];
    if (hasT) {
#pragma unroll
        for (int ti = 0; ti < 2; ti++) {
            int tt = ti ? t1 : t0;
#pragma unroll
            for (int ks = 0; ks < KS; ks++) {
                long off = (long)(tt * 16 + li) * L + ks * 32 + quad * 8;
                Ah[ti][ks] = *(const short8*)(wt_hi + off);
                Al[ti][ks] = *(const short8*)(wt_lo + off);
            }
#pragma unroll
            for (int r = 0; r < 4; r++)
                bias_r[ti][r] = bias[tt * 16 + quad * 4 + r];
        }
    }

    const int nb0 = blockIdx.x * 256;
    float* myscr = scr[w];
    unsigned int* su = (unsigned int*)myscr;

    float4 xv[SI];
    auto issue_loads = [&](int c) {
#pragma unroll
        for (int s = 0; s < SI; s++) {
            int f = s * 256 + tid;
            int row = f / (L / 4), c4 = (f - row * (L / 4)) * 4;
            int n = nb0 + c * 32 + row;
            xv[s] = (n < N) ? *(const float4*)(xin + (long)n * L + c4)
                            : make_float4(0.f, 0.f, 0.f, 0.f);
        }
    };
    auto cvt_store = [&](int buf) {
#pragma unroll
        for (int s = 0; s < SI; s++) {
            int f = s * 256 + tid;
            int row = f / (L / 4), c4 = (f - row * (L / 4)) * 4;
            unsigned short h0 = f2bf(xv[s].x), h1 = f2bf(xv[s].y),
                           h2 = f2bf(xv[s].z), h3 = f2bf(xv[s].w);
            ushort4v hs = {h0, h1, h2, h3};
            ushort4v ls = {f2bf(xv[s].x - bf2f(h0)), f2bf(xv[s].y - bf2f(h1)),
                           f2bf(xv[s].z - bf2f(h2)), f2bf(xv[s].w - bf2f(h3))};
            *(ushort4v*)(xh[buf] + row * LP + c4) = hs;
            *(ushort4v*)(xl[buf] + row * LP + c4) = ls;
        }
    };

    issue_loads(0);
    cvt_store(0);
    __syncthreads();

    for (int c = 0; c < 8; c++) {
        if (c < 7) issue_loads(c + 1);
        const int n0c = nb0 + c * 32;
        if (hasT) {
            const int buf = c & 1;
#pragma unroll
            for (int half = 0; half < 2; half++) {
                short8 Bh[KS], Bl[KS];
#pragma unroll
                for (int ks = 0; ks < KS; ks++) {
                    int off = (half * 16 + li) * LP + ks * 32 + quad * 8;
                    Bh[ks] = *(const short8*)(xh[buf] + off);
                    Bl[ks] = *(const short8*)(xl[buf] + off);
                }
                floatx4 accv[2];
#pragma unroll
                for (int ti = 0; ti < 2; ti++) {
                    floatx4 acc = {0.f, 0.f, 0.f, 0.f};
#pragma unroll
                    for (int ks = 0; ks < KS; ks++) {
                        acc = __builtin_amdgcn_mfma_f32_16x16x32_bf16(Ah[ti][ks], Bh[ks], acc, 0, 0, 0);
                        acc = __builtin_amdgcn_mfma_f32_16x16x32_bf16(Ah[ti][ks], Bl[ks], acc, 0, 0, 0);
                        acc = __builtin_amdgcn_mfma_f32_16x16x32_bf16(Al[ti][ks], Bh[ks], acc, 0, 0, 0);
                    }
#pragma unroll
                    for (int r = 0; r < 4; r++) acc[r] += bias_r[ti][r];
                    accv[ti] = acc;
                }
                const int row = half * 16 + li;
                if (slot < 4 || slot == 12) {
                    *(floatx4*)(myscr + row * 36 + quad * 4)      = accv[0];
                    *(floatx4*)(myscr + row * 36 + 16 + quad * 4) = accv[1];
                } else {
                    unsigned int k01 = (unsigned int)f2bf(accv[0][0]) | ((unsigned int)f2bf(accv[0][1]) << 16);
                    unsigned int k23 = (unsigned int)f2bf(accv[0][2]) | ((unsigned int)f2bf(accv[0][3]) << 16);
                    unsigned int v01 = (unsigned int)f2bf(accv[1][0]) | ((unsigned int)f2bf(accv[1][1]) << 16);
                    unsigned int v23 = (unsigned int)f2bf(accv[1][2]) | ((unsigned int)f2bf(accv[1][3]) << 16);
                    uint4 pk = make_uint4(k01, v01, k23, v23);
                    *(uint4*)(su + row * 20 + quad * 4) = pk;
                }
            }
            if (slot < 4) {
#pragma unroll
                for (int it = 0; it < 4; it++) {
                    int idx = it * 64 + lane;
                    int nl = idx >> 3, seg = idx & 7;
                    int node = n0c + nl;
                    if (node < N) {
                        floatx4 vv = *(floatx4*)(myscr + nl * 36 + seg * 4);
                        *(floatx4*)(q + (long)node * 128 + slot * 32 + seg * 4) = vv;
                    }
                }
            } else if (slot == 12) {
#pragma unroll
                for (int it = 0; it < 4; it++) {
                    int idx = it * 64 + lane;
                    int nl = idx >> 3, seg = idx & 7;
                    int node = n0c + nl;
                    if (node < N) {
                        floatx4 vv = *(floatx4*)(myscr + nl * 36 + seg * 4);
                        *(floatx4*)(skip + (long)node * 32 + seg * 4) = vv;
                    }
                }
            } else {
                const int i = slot - 4;
#pragma unroll
                for (int it = 0; it < 2; it++) {
                    int idx = it * 64 + lane;
                    int nl = idx >> 2, part = idx & 3;
                    int node = n0c + nl;
                    if (node < N) {
                        uint4 vv = *(uint4*)(su + nl * 20 + part * 4);
                        *(uint4*)((unsigned int*)(kvp + (long)node * 256) + i * 16 + part * 4) = vv;
                    }
                }
            }
        }
        __syncthreads();
        if (c < 7) cvt_store((c + 1) & 1);
        __syncthreads();
    }
}

// ---------------- K2: fused attention, 2 edges/wave ----------------
// Wave = 1 dst node. lane = [eh:1][head:2][g:3]: edge-half eh processes half
// the row; lane owns dims hh*32 + 4g..4g+3 (head hh). Per edge per lane: one
// uint4 = [k01,v01,k23,v23] at uint index hh*32+g*4 (16 B); dot-reduce via
// shfl_xor 1/2/4 (8 lanes/head); online-softmax state per lane (replicated
// x8); halves merged via shfl_xor 32; head-mean via shfl_xor 8/16.
// -1e30 floor guards empty halves.
__global__ __launch_bounds__(256) void attn_kernel(
    const float* __restrict__ q, const unsigned short* __restrict__ kvp,
    const int* __restrict__ rowptr, const int* __restrict__ perm,
    const float* __restrict__ skip, float* __restrict__ h, int N)
{
    const int wid = (blockIdx.x * 256 + threadIdx.x) >> 6;
    const int lane = threadIdx.x & 63;
    if (wid >= N) return;
    const int d = __builtin_amdgcn_readfirstlane(wid);
    const int eh = lane >> 5;
    const int sl = lane & 31;
    const int hh = sl >> 3;
    const int g  = sl & 7;
    const int dimoff = hh * 64 + g * 8;    // ushort offset of this lane's 4 dims (x2 for k+v pairs)
    const float4 q4 = *(const float4*)(q + (long)d * 128 + hh * 32 + g * 4);
    const int beg = rowptr[d], end = rowptr[d + 1];
    const int n = end - beg;
    const int na = (n + 1) >> 1;
    const int my_off = beg + (eh ? na : 0);
    const int my_cnt = eh ? (n - na) : na;
    const float scale = 0.17677669529663687f;  // 1/sqrt(32)
    float m = -INFINITY, den = 0.f;
    float o0 = 0.f, o1 = 0.f, o2 = 0.f, o3 = 0.f;
    for (int j = 0; j < na; j += 2) {
        const bool ok0 = j < my_cnt, ok1 = (j + 1) < my_cnt;
        const int i0 = ok0 ? (my_off + j) : beg;
        const int i1 = ok1 ? (my_off + j + 1) : beg;
        const int s0 = perm[i0], s1 = perm[i1];
        const uint4 a0 = *(const uint4*)(kvp + (long)s0 * 256 + dimoff);
        const uint4 a1 = *(const uint4*)(kvp + (long)s1 * 256 + dimoff);
        float p0 = q4.x * blo(a0.x) + q4.y * bhi(a0.x) + q4.z * blo(a0.z) + q4.w * bhi(a0.z);
        float p1 = q4.x * blo(a1.x) + q4.y * bhi(a1.x) + q4.z * blo(a1.z) + q4.w * bhi(a1.z);
        p0 += __shfl_xor(p0, 1);  p1 += __shfl_xor(p1, 1);
        p0 += __shfl_xor(p0, 2);  p1 += __shfl_xor(p1, 2);
        p0 += __shfl_xor(p0, 4);  p1 += __shfl_xor(p1, 4);
        const float l0 = ok0 ? p0 * scale : -INFINITY;
        const float l1 = ok1 ? p1 * scale : -INFINITY;
        const float nm = fmaxf(fmaxf(m, fmaxf(l0, l1)), -1e30f);
        const float sc = __expf(m - nm);
        const float w0 = __expf(l0 - nm);
        const float w1 = __expf(l1 - nm);
        den = den * sc + w0 + w1;
        o0 = o0 * sc + w0 * blo(a0.y) + w1 * blo(a1.y);
        o1 = o1 * sc + w0 * bhi(a0.y) + w1 * bhi(a1.y);
        o2 = o2 * sc + w0 * blo(a0.w) + w1 * blo(a1.w);
        o3 = o3 * sc + w0 * bhi(a0.w) + w1 * bhi(a1.w);
        m = nm;
    }
    // merge the two halves (shfl_xor 32)
    {
        const float mo = __shfl_xor(m, 32);
        const float dn = __shfl_xor(den, 32);
        const float b0 = __shfl_xor(o0, 32);
        const float b1 = __shfl_xor(o1, 32);
        const float b2 = __shfl_xor(o2, 32);
        const float b3 = __shfl_xor(o3, 32);
        const float nm = fmaxf(fmaxf(m, mo), -1e30f);
        const float sa = __expf(m - nm);
        const float sb = __expf(mo - nm);
        den = den * sa + dn * sb;
        o0 = o0 * sa + b0 * sb;
        o1 = o1 * sa + b1 * sb;
        o2 = o2 * sa + b2 * sb;
        o3 = o3 * sa + b3 * sb;
    }
    const float inv = 1.f / (den + 1e-16f);
    o0 *= inv; o1 *= inv; o2 *= inv; o3 *= inv;
    // head mean: sum over head groups (xor 8, 16), then /4
    o0 += __shfl_xor(o0, 8);  o1 += __shfl_xor(o1, 8);
    o2 += __shfl_xor(o2, 8);  o3 += __shfl_xor(o3, 8);
    o0 += __shfl_xor(o0, 16); o1 += __shfl_xor(o1, 16);
    o2 += __shfl_xor(o2, 16); o3 += __shfl_xor(o3, 16);
    if (lane < 8) {
        float4 sk = *(const float4*)(skip + (long)d * 32 + g * 4);
        float r0 = 0.25f * o0 + sk.x;
        float r1 = 0.25f * o1 + sk.y;
        float r2 = 0.25f * o2 + sk.z;
        float r3 = 0.25f * o3 + sk.w;
        r0 = r0 > 0.f ? r0 : 0.f;
        r1 = r1 > 0.f ? r1 : 0.f;
        r2 = r2 > 0.f ? r2 : 0.f;
        r3 = r3 > 0.f ? r3 : 0.f;
        *(float4*)(h + (long)d * 32 + g * 4) = make_float4(r0, r1, r2, r3);
    }
}

// ---------------- K3: final classifier [N,32] @ [32,40] + bc ----------------
__global__ __launch_bounds__(256) void classify_kernel(
    const float* __restrict__ h, const float* __restrict__ wc,
    const float* __restrict__ bc, float* __restrict__ out, int N)
{
    int gid = blockIdx.x * blockDim.x + threadIdx.x;
    if (gid >= N * 40) return;
    int n = gid / 40, o = gid - (gid / 40) * 40;
    float acc = bc[o];
    const float* hr = h + (long)n * 32;
#pragma unroll
    for (int l = 0; l < 32; ++l) acc += hr[l] * wc[l * 40 + o];
    out[gid] = acc;
}

extern "C" void kernel_launch(void* const* d_in, const int* in_sizes, int n_in,
                              void* d_out, int out_size, void* d_ws, size_t ws_size,
                              hipStream_t stream)
{
    const float* x   = (const float*)d_in[0];
    const int* ei    = (const int*)d_in[1];
    const float* wq1 = (const float*)d_in[2];  const float* bq1 = (const float*)d_in[3];
    const float* wk1 = (const float*)d_in[4];  const float* bk1 = (const float*)d_in[5];
    const float* wv1 = (const float*)d_in[6];  const float* bv1 = (const float*)d_in[7];
    const float* ws1 = (const float*)d_in[8];  const float* bs1 = (const float*)d_in[9];
    const float* wq2 = (const float*)d_in[10]; const float* bq2 = (const float*)d_in[11];
    const float* wk2 = (const float*)d_in[12]; const float* bk2 = (const float*)d_in[13];
    const float* wv2 = (const float*)d_in[14]; const float* bv2 = (const float*)d_in[15];
    const float* ws2 = (const float*)d_in[16]; const float* bs2 = (const float*)d_in[17];
    const float* wc  = (const float*)d_in[18]; const float* bc  = (const float*)d_in[19];

    const int N = in_sizes[0] / 128;   // 50000
    const int E = in_sizes[1] / 2;     // 800000
    const int* src = ei;
    const int* dst = ei + E;

    // workspace layout (bytes, 256-aligned chunks)
    char* p = (char*)d_ws;
    auto take = [&](size_t bytes) { char* r = p; p += (bytes + 255) & ~(size_t)255; return r; };
    float* q             = (float*)take((size_t)N * 128 * 4);
    unsigned short* kvp  = (unsigned short*)take((size_t)N * 256 * 2);
    float* skip          = (float*)take((size_t)N * 32 * 4);
    float* h1            = (float*)take((size_t)N * 32 * 4);
    float* h2            = (float*)take((size_t)N * 32 * 4);
    unsigned short* wt1h = (unsigned short*)take(416 * 128 * 2);
    unsigned short* wt1l = (unsigned short*)take(416 * 128 * 2);
    unsigned short* wt2h = (unsigned short*)take(416 * 32 * 2);
    unsigned short* wt2l = (unsigned short*)take(416 * 32 * 2);
    float* bias1         = (float*)take(416 * 4);
    float* bias2         = (float*)take(416 * 4);
    int* deg             = (int*)take((size_t)N * 4);
    int* rowptr          = (int*)take((size_t)(N + 1) * 4);
    int* cursor          = (int*)take((size_t)N * 4);
    int* perm            = (int*)take((size_t)E * 4);
    int* bsum            = (int*)take(64 * 4);
    int* boff            = (int*)take(64 * 4);

    const dim3 projGrid((N + 255) / 256, 4);
    const int eGrid    = (E + 255) / 256;
    const int attnGrid = (N + 3) / 4;          // 4 waves/block
    const int nb       = (N + 1023) / 1024;    // <= 64

    // ---------------- weight prep + CSR build ----------------
    wprep_all<<<832, 128, 0, stream>>>(wq1, bq1, wk1, bk1, wv1, bv1, ws1, bs1,
                                       wq2, bq2, wk2, bk2, wv2, bv2, ws2, bs2,
                                       wt1h, wt1l, bias1, wt2h, wt2l, bias2);
    hipMemsetAsync(deg, 0, (size_t)N * 4, stream);
    hist_kernel<<<eGrid, 256, 0, stream>>>(dst, deg, E);
    scan_part<<<nb, 256, 0, stream>>>(deg, bsum, N);
    scan_tops<<<1, 64, 0, stream>>>(bsum, boff, rowptr, nb, N);
    scan_final<<<nb, 256, 0, stream>>>(deg, boff, rowptr, cursor, N);
    fill_kernel<<<eGrid, 256, 0, stream>>>(src, dst, cursor, perm, E);

    // ---------------- layer 1 ----------------
    proj_mfma<128><<<projGrid, 256, 0, stream>>>(x, wt1h, wt1l, bias1, q, kvp, skip, N);
    attn_kernel<<<attnGrid, 256, 0, stream>>>(q, kvp, rowptr, perm, skip, h1, N);

    // ---------------- layer 2 ----------------
    proj_mfma<32><<<projGrid, 256, 0, stream>>>(h1, wt2h, wt2l, bias2, q, kvp, skip, N);
    attn_kernel<<<attnGrid, 256, 0, stream>>>(q, kvp, rowptr, perm, skip, h2, N);

    // ---------------- classifier ----------------
    classify_kernel<<<(N * 40 + 255) / 256, 256, 0, stream>>>(h2, wc, bc, (float*)d_out, N);
}

// Round 12
// 360.006 us; speedup vs baseline: 1.9645x; 1.0541x over previous
//
#include <hip/hip_runtime.h>
#include <hip/hip_bf16.h>

typedef __attribute__((ext_vector_type(8))) short short8;       // 8 bf16 (A/B frag)
typedef __attribute__((ext_vector_type(4))) float floatx4;      // C/D frag
typedef __attribute__((ext_vector_type(4))) unsigned short ushort4v;

__device__ inline unsigned short f2bf(float x) {                 // RNE f32->bf16 bits
    unsigned int u = __float_as_uint(x);
    u += 0x7FFFu + ((u >> 16) & 1u);
    return (unsigned short)(u >> 16);
}
__device__ inline float bf2f(unsigned short h) {
    return __uint_as_float(((unsigned int)h) << 16);
}
__device__ inline float blo(unsigned int u) { return __uint_as_float(u << 16); }
__device__ inline float bhi(unsigned int u) { return __uint_as_float(u & 0xFFFF0000u); }

// ---------------- CSR build ----------------
__global__ __launch_bounds__(256) void hist_kernel(
    const int* __restrict__ dst, int* __restrict__ deg, int E)
{
    int e = blockIdx.x * blockDim.x + threadIdx.x;
    if (e < E) atomicAdd(&deg[dst[e]], 1);
}

// hierarchical scan: block sums -> top scan (<=64 blocks) -> add-back
__global__ __launch_bounds__(256) void scan_part(
    const int* __restrict__ deg, int* __restrict__ bsum, int N)
{
    __shared__ int ws[4];
    const int base = blockIdx.x * 1024;
    const int tid = threadIdx.x, lane = tid & 63, w = tid >> 6;
    int s = 0;
#pragma unroll
    for (int j = 0; j < 4; j++) {
        int i = base + j * 256 + tid;
        if (i < N) s += deg[i];
    }
#pragma unroll
    for (int off = 1; off < 64; off <<= 1) s += __shfl_xor(s, off, 64);
    if (lane == 0) ws[w] = s;
    __syncthreads();
    if (tid == 0) bsum[blockIdx.x] = ws[0] + ws[1] + ws[2] + ws[3];
}

__global__ __launch_bounds__(64) void scan_tops(
    const int* __restrict__ bsum, int* __restrict__ boff,
    int* __restrict__ rowptr, int nb, int N)
{
    int lane = threadIdx.x;
    int v = (lane < nb) ? bsum[lane] : 0;
    int inc = v;
#pragma unroll
    for (int off = 1; off < 64; off <<= 1) {
        int t = __shfl_up(inc, off, 64);
        if (lane >= off) inc += t;
    }
    if (lane < nb) boff[lane] = inc - v;
    if (lane == 63) rowptr[N] = inc;
}

__global__ __launch_bounds__(256) void scan_final(
    const int* __restrict__ deg, const int* __restrict__ boff,
    int* __restrict__ rowptr, int* __restrict__ cursor, int N)
{
    __shared__ int woff[4];
    const int base = blockIdx.x * 1024;
    const int tid = threadIdx.x, lane = tid & 63, w = tid >> 6;
    const int i0 = base + tid * 4;
    int v0 = (i0     < N) ? deg[i0]     : 0;
    int v1 = (i0 + 1 < N) ? deg[i0 + 1] : 0;
    int v2 = (i0 + 2 < N) ? deg[i0 + 2] : 0;
    int v3 = (i0 + 3 < N) ? deg[i0 + 3] : 0;
    int ts = v0 + v1 + v2 + v3;
    int inc = ts;
#pragma unroll
    for (int off = 1; off < 64; off <<= 1) {
        int t = __shfl_up(inc, off, 64);
        if (lane >= off) inc += t;
    }
    if (lane == 63) woff[w] = inc;
    __syncthreads();
    int wpre = 0;
    if (w > 0) wpre += woff[0];
    if (w > 1) wpre += woff[1];
    if (w > 2) wpre += woff[2];
    int exc = boff[blockIdx.x] + wpre + inc - ts;
    int p0 = exc, p1 = exc + v0, p2 = p1 + v1, p3 = p2 + v2;
    if (i0     < N) { rowptr[i0]     = p0; cursor[i0]     = p0; }
    if (i0 + 1 < N) { rowptr[i0 + 1] = p1; cursor[i0 + 1] = p1; }
    if (i0 + 2 < N) { rowptr[i0 + 2] = p2; cursor[i0 + 2] = p2; }
    if (i0 + 3 < N) { rowptr[i0 + 3] = p3; cursor[i0 + 3] = p3; }
}

__global__ __launch_bounds__(256) void fill_kernel(
    const int* __restrict__ src, const int* __restrict__ dst,
    int* __restrict__ cursor, int* __restrict__ perm, int E)
{
    int e = blockIdx.x * blockDim.x + threadIdx.x;
    if (e >= E) return;
    int pos = atomicAdd(&cursor[dst[e]], 1);
    perm[pos] = src[e];
}

// ---------------- weight prep (both layers fused): Wt[col][k] hi/lo bf16 ----
__global__ __launch_bounds__(128) void wprep_all(
    const float* __restrict__ wq1, const float* __restrict__ bq1,
    const float* __restrict__ wk1, const float* __restrict__ bk1,
    const float* __restrict__ wv1, const float* __restrict__ bv1,
    const float* __restrict__ ws1, const float* __restrict__ bs1,
    const float* __restrict__ wq2, const float* __restrict__ bq2,
    const float* __restrict__ wk2, const float* __restrict__ bk2,
    const float* __restrict__ wv2, const float* __restrict__ bv2,
    const float* __restrict__ ws2, const float* __restrict__ bs2,
    unsigned short* __restrict__ wt1h, unsigned short* __restrict__ wt1l,
    float* __restrict__ bias1,
    unsigned short* __restrict__ wt2h, unsigned short* __restrict__ wt2l,
    float* __restrict__ bias2)
{
    const int layer = (blockIdx.x >= 416) ? 1 : 0;
    const int c = blockIdx.x - layer * 416;
    const int t = threadIdx.x;
    const int L = layer ? 32 : 128;
    if (t >= L) return;
    const float* w; const float* b; int cc, ncols;
    if (c < 384) {
        int m = c >> 7; cc = c & 127; ncols = 128;
        if (layer == 0) {
            w = (m == 0) ? wq1 : ((m == 1) ? wk1 : wv1);
            b = (m == 0) ? bq1 : ((m == 1) ? bk1 : bv1);
        } else {
            w = (m == 0) ? wq2 : ((m == 1) ? wk2 : wv2);
            b = (m == 0) ? bq2 : ((m == 1) ? bk2 : bv2);
        }
    } else {
        cc = c - 384; ncols = 32;
        w = layer ? ws2 : ws1; b = layer ? bs2 : bs1;
    }
    unsigned short* wh = layer ? wt2h : wt1h;
    unsigned short* wl = layer ? wt2l : wt1l;
    float* bias = layer ? bias2 : bias1;
    float val = w[t * ncols + cc];
    unsigned short h = f2bf(val);
    wh[c * L + t] = h;
    wl[c * L + t] = f2bf(val - bf2f(h));
    if (t == 0) bias[c] = b[cc];
}

// ---------------- K1: MFMA projection, A-stationary, coalesced stores -------
// (unchanged from R9/R11 — see comments there)
template <int L>
__global__ __launch_bounds__(256) void proj_mfma(
    const float* __restrict__ xin,
    const unsigned short* __restrict__ wt_hi,
    const unsigned short* __restrict__ wt_lo,
    const float* __restrict__ bias,
    float* __restrict__ q, unsigned short* __restrict__ kvp,
    float* __restrict__ skip, int N)
{
    constexpr int LP = L + 8;          // ushort pad
    constexpr int KS = L / 32;
    constexpr int SI = (32 * (L / 4)) / 256;
    __shared__ unsigned short xh[2][32 * LP];
    __shared__ unsigned short xl[2][32 * LP];
    __shared__ float scr[4][32 * 36];
    const int tid = threadIdx.x, lane = tid & 63, w = tid >> 6;
    const int li = lane & 15, quad = lane >> 4;
    const int slot = __builtin_amdgcn_readfirstlane(blockIdx.y * 4 + w);
    const bool hasT = slot < 13;

    int t0 = 24, t1 = 25;
    if (slot < 4)       { t0 = slot * 2; t1 = t0 + 1; }
    else if (slot < 12) { t0 = 4 + slot; t1 = 12 + slot; }   // k=8+i, v=16+i

    short8 Ah[2][KS], Al[2][KS];
    float bias_r[2][4];
    if (hasT) {
#pragma unroll
        for (int ti = 0; ti < 2; ti++) {
            int tt = ti ? t1 : t0;
#pragma unroll
            for (int ks = 0; ks < KS; ks++) {
                long off = (long)(tt * 16 + li) * L + ks * 32 + quad * 8;
                Ah[ti][ks] = *(const short8*)(wt_hi + off);
                Al[ti][ks] = *(const short8*)(wt_lo + off);
            }
#pragma unroll
            for (int r = 0; r < 4; r++)
                bias_r[ti][r] = bias[tt * 16 + quad * 4 + r];
        }
    }

    const int nb0 = blockIdx.x * 256;
    float* myscr = scr[w];
    unsigned int* su = (unsigned int*)myscr;

    float4 xv[SI];
    auto issue_loads = [&](int c) {
#pragma unroll
        for (int s = 0; s < SI; s++) {
            int f = s * 256 + tid;
            int row = f / (L / 4), c4 = (f - row * (L / 4)) * 4;
            int n = nb0 + c * 32 + row;
            xv[s] = (n < N) ? *(const float4*)(xin + (long)n * L + c4)
                            : make_float4(0.f, 0.f, 0.f, 0.f);
        }
    };
    auto cvt_store = [&](int buf) {
#pragma unroll
        for (int s = 0; s < SI; s++) {
            int f = s * 256 + tid;
            int row = f / (L / 4), c4 = (f - row * (L / 4)) * 4;
            unsigned short h0 = f2bf(xv[s].x), h1 = f2bf(xv[s].y),
                           h2 = f2bf(xv[s].z), h3 = f2bf(xv[s].w);
            ushort4v hs = {h0, h1, h2, h3};
            ushort4v ls = {f2bf(xv[s].x - bf2f(h0)), f2bf(xv[s].y - bf2f(h1)),
                           f2bf(xv[s].z - bf2f(h2)), f2bf(xv[s].w - bf2f(h3))};
            *(ushort4v*)(xh[buf] + row * LP + c4) = hs;
            *(ushort4v*)(xl[buf] + row * LP + c4) = ls;
        }
    };

    issue_loads(0);
    cvt_store(0);
    __syncthreads();

    for (int c = 0; c < 8; c++) {
        if (c < 7) issue_loads(c + 1);
        const int n0c = nb0 + c * 32;
        if (hasT) {
            const int buf = c & 1;
#pragma unroll
            for (int half = 0; half < 2; half++) {
                short8 Bh[KS], Bl[KS];
#pragma unroll
                for (int ks = 0; ks < KS; ks++) {
                    int off = (half * 16 + li) * LP + ks * 32 + quad * 8;
                    Bh[ks] = *(const short8*)(xh[buf] + off);
                    Bl[ks] = *(const short8*)(xl[buf] + off);
                }
                floatx4 accv[2];
#pragma unroll
                for (int ti = 0; ti < 2; ti++) {
                    floatx4 acc = {0.f, 0.f, 0.f, 0.f};
#pragma unroll
                    for (int ks = 0; ks < KS; ks++) {
                        acc = __builtin_amdgcn_mfma_f32_16x16x32_bf16(Ah[ti][ks], Bh[ks], acc, 0, 0, 0);
                        acc = __builtin_amdgcn_mfma_f32_16x16x32_bf16(Ah[ti][ks], Bl[ks], acc, 0, 0, 0);
                        acc = __builtin_amdgcn_mfma_f32_16x16x32_bf16(Al[ti][ks], Bh[ks], acc, 0, 0, 0);
                    }
#pragma unroll
                    for (int r = 0; r < 4; r++) acc[r] += bias_r[ti][r];
                    accv[ti] = acc;
                }
                const int row = half * 16 + li;
                if (slot < 4 || slot == 12) {
                    *(floatx4*)(myscr + row * 36 + quad * 4)      = accv[0];
                    *(floatx4*)(myscr + row * 36 + 16 + quad * 4) = accv[1];
                } else {
                    unsigned int k01 = (unsigned int)f2bf(accv[0][0]) | ((unsigned int)f2bf(accv[0][1]) << 16);
                    unsigned int k23 = (unsigned int)f2bf(accv[0][2]) | ((unsigned int)f2bf(accv[0][3]) << 16);
                    unsigned int v01 = (unsigned int)f2bf(accv[1][0]) | ((unsigned int)f2bf(accv[1][1]) << 16);
                    unsigned int v23 = (unsigned int)f2bf(accv[1][2]) | ((unsigned int)f2bf(accv[1][3]) << 16);
                    uint4 pk = make_uint4(k01, v01, k23, v23);
                    *(uint4*)(su + row * 20 + quad * 4) = pk;
                }
            }
            if (slot < 4) {
#pragma unroll
                for (int it = 0; it < 4; it++) {
                    int idx = it * 64 + lane;
                    int nl = idx >> 3, seg = idx & 7;
                    int node = n0c + nl;
                    if (node < N) {
                        floatx4 vv = *(floatx4*)(myscr + nl * 36 + seg * 4);
                        *(floatx4*)(q + (long)node * 128 + slot * 32 + seg * 4) = vv;
                    }
                }
            } else if (slot == 12) {
#pragma unroll
                for (int it = 0; it < 4; it++) {
                    int idx = it * 64 + lane;
                    int nl = idx >> 3, seg = idx & 7;
                    int node = n0c + nl;
                    if (node < N) {
                        floatx4 vv = *(floatx4*)(myscr + nl * 36 + seg * 4);
                        *(floatx4*)(skip + (long)node * 32 + seg * 4) = vv;
                    }
                }
            } else {
                const int i = slot - 4;
#pragma unroll
                for (int it = 0; it < 2; it++) {
                    int idx = it * 64 + lane;
                    int nl = idx >> 2, part = idx & 3;
                    int node = n0c + nl;
                    if (node < N) {
                        uint4 vv = *(uint4*)(su + nl * 20 + part * 4);
                        *(uint4*)((unsigned int*)(kvp + (long)node * 256) + i * 16 + part * 4) = vv;
                    }
                }
            }
        }
        __syncthreads();
        if (c < 7) cvt_store((c + 1) & 1);
        __syncthreads();
    }
}

// ---------------- K2: fused attention, software-pipelined gathers ----------
// Wave = 1 dst node. lane = [eh:1][head:2][g:3]; lane owns dims hh*32+4g..+3.
// 4 edges/half per iteration; perm prefetched 2 iters ahead, kv rows 1 iter
// ahead (branch-free, indices clamped). Halves merged via shfl_xor 32;
// head-mean via shfl_xor 8/16. FUSE_CLS: classifier fused in epilogue.
template <bool FUSE_CLS>
__global__ __launch_bounds__(256) void attn_kernel(
    const float* __restrict__ q, const unsigned short* __restrict__ kvp,
    const int* __restrict__ rowptr, const int* __restrict__ perm,
    const float* __restrict__ skip, float* __restrict__ h,
    const float* __restrict__ wc, const float* __restrict__ bc,
    float* __restrict__ out, int N, int E)
{
    __shared__ float hrow[4][32];
    const int wid = (blockIdx.x * 256 + threadIdx.x) >> 6;
    const int wv = (threadIdx.x >> 6) & 3;
    const int lane = threadIdx.x & 63;
    if (wid >= N) return;
    const int d = __builtin_amdgcn_readfirstlane(wid);
    const int eh = lane >> 5;
    const int sl = lane & 31;
    const int hh = sl >> 3;
    const int g  = sl & 7;
    const int dimoff = hh * 64 + g * 8;
    const float4 q4 = *(const float4*)(q + (long)d * 128 + hh * 32 + g * 4);
    const int beg = rowptr[d], end = rowptr[d + 1];
    const int n = end - beg;
    const int na = (n + 1) >> 1;
    const int my_off = beg + (eh ? na : 0);
    const int my_cnt = eh ? (n - na) : na;
    const float scale = 0.17677669529663687f;  // 1/sqrt(32)
    float m = -INFINITY, den = 0.f;
    float o0 = 0.f, o1 = 0.f, o2 = 0.f, o3 = 0.f;

    auto eidx = [&](int j) -> int {
        int i = (j < my_cnt) ? (my_off + j) : beg;
        return (i < E) ? i : 0;
    };

    // pipeline prime: perm for j=0..7, kv for j=0..3
    int P0 = perm[eidx(4)], P1 = perm[eidx(5)], P2 = perm[eidx(6)], P3 = perm[eidx(7)];
    uint4 A0, A1, A2, A3;
    {
        int s0 = perm[eidx(0)], s1 = perm[eidx(1)], s2 = perm[eidx(2)], s3 = perm[eidx(3)];
        A0 = *(const uint4*)(kvp + (long)s0 * 256 + dimoff);
        A1 = *(const uint4*)(kvp + (long)s1 * 256 + dimoff);
        A2 = *(const uint4*)(kvp + (long)s2 * 256 + dimoff);
        A3 = *(const uint4*)(kvp + (long)s3 * 256 + dimoff);
    }

    for (int j = 0; j < na; j += 4) {
        // prefetch: kv for j+4 (via P), perm for j+8
        uint4 B0 = *(const uint4*)(kvp + (long)P0 * 256 + dimoff);
        uint4 B1 = *(const uint4*)(kvp + (long)P1 * 256 + dimoff);
        uint4 B2 = *(const uint4*)(kvp + (long)P2 * 256 + dimoff);
        uint4 B3 = *(const uint4*)(kvp + (long)P3 * 256 + dimoff);
        int NP0 = perm[eidx(j + 8)],  NP1 = perm[eidx(j + 9)];
        int NP2 = perm[eidx(j + 10)], NP3 = perm[eidx(j + 11)];

        float p0 = q4.x * blo(A0.x) + q4.y * bhi(A0.x) + q4.z * blo(A0.z) + q4.w * bhi(A0.z);
        float p1 = q4.x * blo(A1.x) + q4.y * bhi(A1.x) + q4.z * blo(A1.z) + q4.w * bhi(A1.z);
        float p2 = q4.x * blo(A2.x) + q4.y * bhi(A2.x) + q4.z * blo(A2.z) + q4.w * bhi(A2.z);
        float p3 = q4.x * blo(A3.x) + q4.y * bhi(A3.x) + q4.z * blo(A3.z) + q4.w * bhi(A3.z);
        p0 += __shfl_xor(p0, 1);  p1 += __shfl_xor(p1, 1);  p2 += __shfl_xor(p2, 1);  p3 += __shfl_xor(p3, 1);
        p0 += __shfl_xor(p0, 2);  p1 += __shfl_xor(p1, 2);  p2 += __shfl_xor(p2, 2);  p3 += __shfl_xor(p3, 2);
        p0 += __shfl_xor(p0, 4);  p1 += __shfl_xor(p1, 4);  p2 += __shfl_xor(p2, 4);  p3 += __shfl_xor(p3, 4);
        const float l0 = (j + 0 < my_cnt) ? p0 * scale : -INFINITY;
        const float l1 = (j + 1 < my_cnt) ? p1 * scale : -INFINITY;
        const float l2 = (j + 2 < my_cnt) ? p2 * scale : -INFINITY;
        const float l3 = (j + 3 < my_cnt) ? p3 * scale : -INFINITY;
        const float mb = fmaxf(fmaxf(l0, l1), fmaxf(l2, l3));
        const float nm = fmaxf(fmaxf(m, mb), -1e30f);
        const float sc = __expf(m - nm);
        const float w0 = __expf(l0 - nm), w1 = __expf(l1 - nm);
        const float w2 = __expf(l2 - nm), w3 = __expf(l3 - nm);
        den = den * sc + ((w0 + w1) + (w2 + w3));
        o0 = o0 * sc + w0 * blo(A0.y) + w1 * blo(A1.y) + w2 * blo(A2.y) + w3 * blo(A3.y);
        o1 = o1 * sc + w0 * bhi(A0.y) + w1 * bhi(A1.y) + w2 * bhi(A2.y) + w3 * bhi(A3.y);
        o2 = o2 * sc + w0 * blo(A0.w) + w1 * blo(A1.w) + w2 * blo(A2.w) + w3 * blo(A3.w);
        o3 = o3 * sc + w0 * bhi(A0.w) + w1 * bhi(A1.w) + w2 * bhi(A2.w) + w3 * bhi(A3.w);
        m = nm;
        A0 = B0; A1 = B1; A2 = B2; A3 = B3;
        P0 = NP0; P1 = NP1; P2 = NP2; P3 = NP3;
    }

    // merge the two halves (shfl_xor 32)
    {
        const float mo = __shfl_xor(m, 32);
        const float dn = __shfl_xor(den, 32);
        const float b0 = __shfl_xor(o0, 32);
        const float b1 = __shfl_xor(o1, 32);
        const float b2 = __shfl_xor(o2, 32);
        const float b3 = __shfl_xor(o3, 32);
        const float nm = fmaxf(fmaxf(m, mo), -1e30f);
        const float sa = __expf(m - nm);
        const float sb = __expf(mo - nm);
        den = den * sa + dn * sb;
        o0 = o0 * sa + b0 * sb;
        o1 = o1 * sa + b1 * sb;
        o2 = o2 * sa + b2 * sb;
        o3 = o3 * sa + b3 * sb;
    }
    const float inv = 1.f / (den + 1e-16f);
    o0 *= inv; o1 *= inv; o2 *= inv; o3 *= inv;
    // head mean: sum over head groups (xor 8, 16), then /4
    o0 += __shfl_xor(o0, 8);  o1 += __shfl_xor(o1, 8);
    o2 += __shfl_xor(o2, 8);  o3 += __shfl_xor(o3, 8);
    o0 += __shfl_xor(o0, 16); o1 += __shfl_xor(o1, 16);
    o2 += __shfl_xor(o2, 16); o3 += __shfl_xor(o3, 16);

    if (lane < 8) {
        float4 sk = *(const float4*)(skip + (long)d * 32 + g * 4);
        float r0 = 0.25f * o0 + sk.x;
        float r1 = 0.25f * o1 + sk.y;
        float r2 = 0.25f * o2 + sk.z;
        float r3 = 0.25f * o3 + sk.w;
        r0 = r0 > 0.f ? r0 : 0.f;
        r1 = r1 > 0.f ? r1 : 0.f;
        r2 = r2 > 0.f ? r2 : 0.f;
        r3 = r3 > 0.f ? r3 : 0.f;
        if (FUSE_CLS) {
            *(float4*)&hrow[wv][g * 4] = make_float4(r0, r1, r2, r3);
        } else {
            *(float4*)(h + (long)d * 32 + g * 4) = make_float4(r0, r1, r2, r3);
        }
    }
    if (FUSE_CLS) {
        __builtin_amdgcn_wave_barrier();   // wave-internal LDS ordering (no HW cost)
        if (lane < 40) {
            float acc = bc[lane];
#pragma unroll
            for (int l = 0; l < 32; ++l)
                acc = fmaf(hrow[wv][l], wc[l * 40 + lane], acc);
            out[(long)d * 40 + lane] = acc;
        }
    }
}

extern "C" void kernel_launch(void* const* d_in, const int* in_sizes, int n_in,
                              void* d_out, int out_size, void* d_ws, size_t ws_size,
                              hipStream_t stream)
{
    const float* x   = (const float*)d_in[0];
    const int* ei    = (const int*)d_in[1];
    const float* wq1 = (const float*)d_in[2];  const float* bq1 = (const float*)d_in[3];
    const float* wk1 = (const float*)d_in[4];  const float* bk1 = (const float*)d_in[5];
    const float* wv1 = (const float*)d_in[6];  const float* bv1 = (const float*)d_in[7];
    const float* ws1 = (const float*)d_in[8];  const float* bs1 = (const float*)d_in[9];
    const float* wq2 = (const float*)d_in[10]; const float* bq2 = (const float*)d_in[11];
    const float* wk2 = (const float*)d_in[12]; const float* bk2 = (const float*)d_in[13];
    const float* wv2 = (const float*)d_in[14]; const float* bv2 = (const float*)d_in[15];
    const float* ws2 = (const float*)d_in[16]; const float* bs2 = (const float*)d_in[17];
    const float* wc  = (const float*)d_in[18]; const float* bc  = (const float*)d_in[19];

    const int N = in_sizes[0] / 128;   // 50000
    const int E = in_sizes[1] / 2;     // 800000
    const int* src = ei;
    const int* dst = ei + E;

    // workspace layout (bytes, 256-aligned chunks)
    char* p = (char*)d_ws;
    auto take = [&](size_t bytes) { char* r = p; p += (bytes + 255) & ~(size_t)255; return r; };
    float* q             = (float*)take((size_t)N * 128 * 4);
    unsigned short* kvp  = (unsigned short*)take((size_t)N * 256 * 2);
    float* skip          = (float*)take((size_t)N * 32 * 4);
    float* h1            = (float*)take((size_t)N * 32 * 4);
    unsigned short* wt1h = (unsigned short*)take(416 * 128 * 2);
    unsigned short* wt1l = (unsigned short*)take(416 * 128 * 2);
    unsigned short* wt2h = (unsigned short*)take(416 * 32 * 2);
    unsigned short* wt2l = (unsigned short*)take(416 * 32 * 2);
    float* bias1         = (float*)take(416 * 4);
    float* bias2         = (float*)take(416 * 4);
    int* deg             = (int*)take((size_t)N * 4);
    int* rowptr          = (int*)take((size_t)(N + 1) * 4);
    int* cursor          = (int*)take((size_t)N * 4);
    int* perm            = (int*)take((size_t)E * 4);
    int* bsum            = (int*)take(64 * 4);
    int* boff            = (int*)take(64 * 4);

    const dim3 projGrid((N + 255) / 256, 4);
    const int eGrid    = (E + 255) / 256;
    const int attnGrid = (N + 3) / 4;          // 4 waves/block
    const int nb       = (N + 1023) / 1024;    // <= 64

    // ---------------- weight prep + CSR build ----------------
    wprep_all<<<832, 128, 0, stream>>>(wq1, bq1, wk1, bk1, wv1, bv1, ws1, bs1,
                                       wq2, bq2, wk2, bk2, wv2, bv2, ws2, bs2,
                                       wt1h, wt1l, bias1, wt2h, wt2l, bias2);
    hipMemsetAsync(deg, 0, (size_t)N * 4, stream);
    hist_kernel<<<eGrid, 256, 0, stream>>>(dst, deg, E);
    scan_part<<<nb, 256, 0, stream>>>(deg, bsum, N);
    scan_tops<<<1, 64, 0, stream>>>(bsum, boff, rowptr, nb, N);
    scan_final<<<nb, 256, 0, stream>>>(deg, boff, rowptr, cursor, N);
    fill_kernel<<<eGrid, 256, 0, stream>>>(src, dst, cursor, perm, E);

    // ---------------- layer 1 ----------------
    proj_mfma<128><<<projGrid, 256, 0, stream>>>(x, wt1h, wt1l, bias1, q, kvp, skip, N);
    attn_kernel<false><<<attnGrid, 256, 0, stream>>>(q, kvp, rowptr, perm, skip, h1,
                                                     wc, bc, (float*)d_out, N, E);

    // ---------------- layer 2 (classifier fused into attn epilogue) --------
    proj_mfma<32><<<projGrid, 256, 0, stream>>>(h1, wt2h, wt2l, bias2, q, kvp, skip, N);
    attn_kernel<true><<<attnGrid, 256, 0, stream>>>(q, kvp, rowptr, perm, skip, h1,
                                                    wc, bc, (float*)d_out, N, E);
}